// Round 16
// baseline (194.750 us; speedup 1.0000x reference)
//
#include <hip/hip_runtime.h>
#include <hip/hip_bf16.h>

typedef __hip_bfloat16 bf16;
typedef __attribute__((ext_vector_type(8))) __bf16 bf16x8;
typedef __attribute__((ext_vector_type(4))) float f32x4;
typedef __attribute__((ext_vector_type(4))) unsigned int u32x4;

static __device__ __forceinline__ float b2f(bf16 x){ return __bfloat162float(x); }
static __device__ __forceinline__ bf16  f2b(float x){ return __float2bfloat16(x); }

constexpr int cB = 2048, cN = 64, cD = 128, cDM = 256, cH = 8, cNE = 6, cNU = 4;
constexpr int cBN = cB * cN;                 // 131072 rows
constexpr float LNEPS = 1e-5f;
constexpr float RSQ32 = 0.17677669529663687f; // 1/sqrt(32)
constexpr int MAXUT = 80;                     // >= 2048/32 + 4
constexpr int cEH = cNE * cH;                 // 48

// kvT swizzle key: varies with BOTH i&7 and (i>>3)&7 so 16-lane staging groups
// (which share n and i&7) spread across 8 banks (2-way = free).
static __device__ __forceinline__ int kvkey(int row){ return ((row ^ (row >> 3)) & 7) << 4; }

// ------------- fused weight prep: Wq/Wv/fc/m1/m2 bf16 convert, Wk transpose -------------
__global__ __launch_bounds__(256) void k_wprep(const float* __restrict__ Wq,
        const float* __restrict__ Wk, const float* __restrict__ Wv,
        const float* __restrict__ fc_w, const float* __restrict__ m1w,
        const float* __restrict__ m2w,
        bf16* __restrict__ Wqb, bf16* __restrict__ Wvb, bf16* __restrict__ WkT,
        bf16* __restrict__ fcwb, bf16* __restrict__ m1wb, bf16* __restrict__ m2wb){
    __shared__ bf16 tile[32][33];
    int y = blockIdx.y, x = blockIdx.x, t = threadIdx.x;
    if (y == 5){
        int e = x >> 6, tb = x & 63;
        int tr = tb >> 3, tc = tb & 7;
        int r = t >> 3, c4 = (t & 7) * 4;
        float4 v = *(const float4*)(Wk + ((size_t)e * 256 + tr * 32 + r) * 256 + tc * 32 + c4);
        tile[r][c4 + 0] = f2b(v.x); tile[r][c4 + 1] = f2b(v.y);
        tile[r][c4 + 2] = f2b(v.z); tile[r][c4 + 3] = f2b(v.w);
        __syncthreads();
        union { bf16 h[4]; uint2 u; } p;
        p.h[0] = tile[c4 + 0][r]; p.h[1] = tile[c4 + 1][r];
        p.h[2] = tile[c4 + 2][r]; p.h[3] = tile[c4 + 3][r];
        *(uint2*)&WkT[((size_t)e * 256 + tc * 32 + r) * 256 + tr * 32 + c4] = p.u;
        return;
    }
    const float* s; bf16* d; int n4;
    switch (y){
        case 0: s = Wq;   d = Wqb;  n4 = cNE * cDM * cDM / 4; break;
        case 1: s = Wv;   d = Wvb;  n4 = cNE * cDM * cDM / 4; break;
        case 2: s = fc_w; d = fcwb; n4 = cNU * cDM * cDM / 4; break;
        case 3: s = m1w;  d = m1wb; n4 = cD * (cDM + cD) / 4; break;
        default: s = m2w; d = m2wb; n4 = cD * cD / 4; break;
    }
    int i = x * 256 + t;
    if (i >= n4) return;
    float4 v = ((const float4*)s)[i];
    union { bf16 h[4]; uint2 u; } p;
    p.h[0] = f2b(v.x); p.h[1] = f2b(v.y); p.h[2] = f2b(v.z); p.h[3] = f2b(v.w);
    *(uint2*)&d[(size_t)i * 4] = p.u;
}

// ---------------- qcatb[b] = bf16([ln1(src[b]), src_t[b]]); srcb = bf16(src) ----------------
__global__ __launch_bounds__(256) void k_qprep(const float* __restrict__ src,
        const float* __restrict__ src_t, const float* __restrict__ g1,
        const float* __restrict__ b1, bf16* __restrict__ qcatb,
        bf16* __restrict__ srcb){
    int lane = threadIdx.x & 63;
    int b = blockIdx.x * 4 + (threadIdx.x >> 6);
    const float* s = src + b * cD;
    float x0 = s[lane], x1 = s[lane + 64];
    srcb[b * cD + lane]      = f2b(x0);
    srcb[b * cD + lane + 64] = f2b(x1);
    float sm = x0 + x1;
    #pragma unroll
    for (int m = 32; m; m >>= 1) sm += __shfl_xor(sm, m);
    float mu = sm * (1.0f / cD);
    float d0 = x0 - mu, d1 = x1 - mu;
    float vs = d0 * d0 + d1 * d1;
    #pragma unroll
    for (int m = 32; m; m >>= 1) vs += __shfl_xor(vs, m);
    float rs = rsqrtf(vs * (1.0f / cD) + LNEPS);
    bf16* q = qcatb + b * cDM;
    q[lane]        = f2b(d0 * rs * g1[lane] + b1[lane]);
    q[lane + 64]   = f2b(d1 * rs * g1[lane + 64] + b1[lane + 64]);
    q[cD + lane]      = f2b(src_t[b * cD + lane]);
    q[cD + lane + 64] = f2b(src_t[b * cD + lane + 64]);
}

// ------------- k_ln: kvecL[row][0:128] = bf16(ln2(seq+seq_e))  (256B rows) -------------
__global__ __launch_bounds__(256) void k_ln(const float* __restrict__ seq,
        const float* __restrict__ seq_e, const float* __restrict__ g2,
        const float* __restrict__ b2v, bf16* __restrict__ kvecL){
    int t = threadIdx.x;
    int l = t & 31, g = t >> 5;
    int row = blockIdx.x * 8 + g;
    float4 a  = *(const float4*)(seq   + (size_t)row * cD + l * 4);
    float4 eV = *(const float4*)(seq_e + (size_t)row * cD + l * 4);
    float x[4] = {a.x + eV.x, a.y + eV.y, a.z + eV.z, a.w + eV.w};
    float sm = (x[0] + x[1]) + (x[2] + x[3]);
    #pragma unroll
    for (int m = 16; m; m >>= 1) sm += __shfl_xor(sm, m);
    float mu = sm * (1.0f / cD), vs = 0.f;
    #pragma unroll
    for (int j = 0; j < 4; ++j){ x[j] -= mu; vs += x[j] * x[j]; }
    #pragma unroll
    for (int m = 16; m; m >>= 1) vs += __shfl_xor(vs, m);
    float rs = rsqrtf(vs * (1.0f / cD) + LNEPS);
    float4 gg = *(const float4*)(g2 + l * 4);
    float4 bb = *(const float4*)(b2v + l * 4);
    union { bf16 h[4]; uint2 u; } p;
    p.h[0] = f2b(x[0] * rs * gg.x + bb.x);
    p.h[1] = f2b(x[1] * rs * gg.y + bb.y);
    p.h[2] = f2b(x[2] * rs * gg.z + bb.z);
    p.h[3] = f2b(x[3] * rs * gg.w + bb.w);
    *(uint2*)&kvecL[(size_t)row * cD + l * 4] = p.u;
}

// ------------- utype gather: counts, index lists, tile list (single block) -------------
__global__ __launch_bounds__(256) void k_uprep(const int* __restrict__ utype,
        int* __restrict__ ucnt, int* __restrict__ uidx,
        int* __restrict__ utiles, int* __restrict__ nutiles){
    __shared__ int lc[cNU], cur[cNU];
    int t = threadIdx.x;
    if (t < cNU){ lc[t] = 0; cur[t] = 0; }
    __syncthreads();
    #pragma unroll
    for (int i = 0; i < 8; ++i) atomicAdd(&lc[utype[t + i * 256]], 1);
    __syncthreads();
    if (t < cNU) ucnt[t] = lc[t];
    #pragma unroll
    for (int i = 0; i < 8; ++i){
        int b = t + i * 256;
        int u = utype[b];
        int pos = atomicAdd(&cur[u], 1);
        uidx[u * cB + pos] = b;
    }
    __syncthreads();
    if (t == 0){
        int s = 0;
        for (int u = 0; u < cNU; ++u){
            int nt = (lc[u] + 31) >> 5;
            for (int k = 0; k < nt; ++k) utiles[s + k] = (u << 16) | k;
            s += nt;
        }
        *nutiles = s;
    }
}

// ------------- Qeb[b][e] = bf16(qcat[b] @ Wq[e].T) via MFMA -------------
__global__ __launch_bounds__(256) void k_gemmQ(const bf16* __restrict__ qcatb,
        const bf16* __restrict__ Wqb, bf16* __restrict__ Qeb){
    int t = threadIdx.x, w = t >> 6, l = t & 63;
    int lr = l & 15, lg4 = l >> 4;
    int b0 = blockIdx.x * 32, e = blockIdx.y;
    const char* A  = (const char*)qcatb + (size_t)b0 * 512;
    const char* Wq = (const char*)(Wqb + (size_t)e * 65536);
    int colbase = w * 64;
    f32x4 acc[2][4] = {};
    #pragma unroll
    for (int ks = 0; ks < 8; ++ks){
        int kb = ks * 64 + lg4 * 16;
        bf16x8 a0 = *(const bf16x8*)(A + (size_t)lr * 512 + kb);
        bf16x8 a1 = *(const bf16x8*)(A + (size_t)(16 + lr) * 512 + kb);
        #pragma unroll
        for (int cf = 0; cf < 4; ++cf){
            bf16x8 bq = *(const bf16x8*)(Wq + (size_t)(colbase + cf * 16 + lr) * 512 + kb);
            acc[0][cf] = __builtin_amdgcn_mfma_f32_16x16x32_bf16(a0, bq, acc[0][cf], 0, 0, 0);
            acc[1][cf] = __builtin_amdgcn_mfma_f32_16x16x32_bf16(a1, bq, acc[1][cf], 0, 0, 0);
        }
    }
    #pragma unroll
    for (int rf = 0; rf < 2; ++rf)
        #pragma unroll
        for (int cf = 0; cf < 4; ++cf)
            #pragma unroll
            for (int j = 0; j < 4; ++j){
                int b = b0 + rf * 16 + lg4 * 4 + j;
                Qeb[((size_t)b * cNE + e) * cDM + colbase + cf * 16 + lr] = f2b(acc[rf][cf][j]);
            }
}

// ------------- qk[b][e][h][:] = (pri/sqrt(32)) * (Qe[b,e,head h] @ Wk[e][head h, :]) -------------
__global__ __launch_bounds__(256) void k_qk(const bf16* __restrict__ Qeb,
        const bf16* __restrict__ WkT, const float* __restrict__ rpri,
        const int* __restrict__ utype, bf16* __restrict__ qk){
    __shared__ float s_pri[32];
    int t = threadIdx.x, w = t >> 6, l = t & 63;
    int lr = l & 15, lg4 = l >> 4;
    int b0 = blockIdx.x * 32, e = blockIdx.y, h = blockIdx.z;
    if (t < 32) s_pri[t] = rpri[utype[b0 + t] * cNE + e] * RSQ32;
    __syncthreads();
    int colbase = w * 64;
    bf16x8 a0 = *(const bf16x8*)(Qeb + ((size_t)(b0 + lr) * cNE + e) * cDM + h * 32 + lg4 * 8);
    bf16x8 a1 = *(const bf16x8*)(Qeb + ((size_t)(b0 + 16 + lr) * cNE + e) * cDM + h * 32 + lg4 * 8);
    f32x4 acc[2][4] = {};
    #pragma unroll
    for (int cf = 0; cf < 4; ++cf){
        bf16x8 bq = *(const bf16x8*)(WkT + ((size_t)e * 256 + colbase + cf * 16 + lr) * 256 + h * 32 + lg4 * 8);
        acc[0][cf] = __builtin_amdgcn_mfma_f32_16x16x32_bf16(a0, bq, acc[0][cf], 0, 0, 0);
        acc[1][cf] = __builtin_amdgcn_mfma_f32_16x16x32_bf16(a1, bq, acc[1][cf], 0, 0, 0);
    }
    #pragma unroll
    for (int rf = 0; rf < 2; ++rf)
        #pragma unroll
        for (int cf = 0; cf < 4; ++cf)
            #pragma unroll
            for (int j = 0; j < 4; ++j){
                int bb = b0 + rf * 16 + lg4 * 4 + j;
                float sc = s_pri[rf * 16 + lg4 * 4 + j];
                qk[(((size_t)bb * cNE + e) * cH + h) * cDM + colbase + cf * 16 + lr]
                    = f2b(acc[rf][cf][j] * sc);
            }
}

// ------------- per-b: logits MFMA, softmax -> outA, s = P'@kv (i-halved), bounce-out -------------
// kvT swizzle key includes (i>>3) so coalesced staging writes are conflict-free.
__global__ __launch_bounds__(256, 5) void k_attn(const bf16* __restrict__ kvecL,
        const float* __restrict__ seq_t, const bf16* __restrict__ qk,
        const int* __restrict__ etype, const int* __restrict__ maskp,
        float* __restrict__ outA, bf16* __restrict__ sbuf){
    __shared__ __align__(16) unsigned char kvT[16384];
    __shared__ __align__(16) unsigned char uB[64 * 49 * 4];
    __shared__ int s_e[cN], s_m[cN];
    int b = blockIdx.x, t = threadIdx.x;
    if (t < cN){ s_e[t] = etype[b * cN + t]; s_m[t] = maskp[b * cN + t]; }
    int w = t >> 6, l = t & 63, lr = l & 15, lg4 = l >> 4;
    const char* kl_ = (const char*)(kvecL + (size_t)b * cN * cD);   // 256B rows
    const char* st_ = (const char*)(seq_t + (size_t)b * cN * cD);   // 512B rows (f32)
    // stage kvT half 0 (i<128) from kvecL: coalesced 16B loads, conflict-free writes
    #pragma unroll
    for (int q = 0; q < 4; ++q){
        int c = t + q * 256;
        int n = c >> 4, il0 = (c & 15) * 8;
        union { u32x4 v; bf16 hh[8]; } pk;
        pk.v = *(const u32x4*)(kl_ + (size_t)n * 256 + il0 * 2);
        #pragma unroll
        for (int j = 0; j < 8; ++j){
            int row = il0 + j;
            *(bf16*)(kvT + row * 128 + ((n * 2) ^ kvkey(row))) = pk.hh[j];
        }
    }
    // logits MFMA: A rows n = w*16+lr; i<128 from kvecL, i>=128 from seq_t (cvt)
    const char* Arow = kl_ + (size_t)(w * 16 + lr) * 256;
    const char* Ast  = st_ + (size_t)(w * 16 + lr) * 512;
    const char* Bq = (const char*)(qk + (size_t)b * (cNE * cH * cDM));
    f32x4 acc[3] = {};
    #pragma unroll
    for (int ks = 0; ks < 4; ++ks){
        int kb = ks * 64 + lg4 * 16;
        bf16x8 af = *(const bf16x8*)(Arow + kb);
        #pragma unroll
        for (int cf = 0; cf < 3; ++cf){
            bf16x8 bq = *(const bf16x8*)(Bq + (size_t)(cf * 16 + lr) * 512 + kb);
            acc[cf] = __builtin_amdgcn_mfma_f32_16x16x32_bf16(af, bq, acc[cf], 0, 0, 0);
        }
    }
    #pragma unroll
    for (int ks = 4; ks < 8; ++ks){
        int kb = ks * 64 + lg4 * 16;
        float4 f0 = *(const float4*)(Ast + kb * 2 - 512);
        float4 f1 = *(const float4*)(Ast + kb * 2 - 496);
        union { bf16x8 v; bf16 hh[8]; } ua;
        ua.hh[0] = f2b(f0.x); ua.hh[1] = f2b(f0.y); ua.hh[2] = f2b(f0.z); ua.hh[3] = f2b(f0.w);
        ua.hh[4] = f2b(f1.x); ua.hh[5] = f2b(f1.y); ua.hh[6] = f2b(f1.z); ua.hh[7] = f2b(f1.w);
        #pragma unroll
        for (int cf = 0; cf < 3; ++cf){
            bf16x8 bq = *(const bf16x8*)(Bq + (size_t)(cf * 16 + lr) * 512 + kb);
            acc[cf] = __builtin_amdgcn_mfma_f32_16x16x32_bf16(ua.v, bq, acc[cf], 0, 0, 0);
        }
    }
    float* lgAll = (float*)uB;
    #pragma unroll
    for (int cf = 0; cf < 3; ++cf)
        #pragma unroll
        for (int j = 0; j < 4; ++j)
            lgAll[(w * 16 + lg4 * 4 + j) * 49 + cf * 16 + lr] = acc[cf][j];
    __syncthreads();                       // lgAll + kvT(0) + s_e ready
    // softmax: wave w handles heads w and w+4; lane l == n
    int n = l;
    int e = s_e[n];
    bool msk = s_m[n] != 0;
    float v0 = msk ? -1e10f : lgAll[n * 49 + e * 8 + w];
    float v1 = msk ? -1e10f : lgAll[n * 49 + e * 8 + w + 4];
    __syncthreads();                       // lgAll dead; uB becomes Pp
    float m0 = v0, m1v = v1;
    #pragma unroll
    for (int m = 32; m; m >>= 1){
        m0 = fmaxf(m0, __shfl_xor(m0, m));
        m1v = fmaxf(m1v, __shfl_xor(m1v, m));
    }
    float e0 = expf(v0 - m0), e1 = expf(v1 - m1v);
    float sm0 = e0, sm1 = e1;
    #pragma unroll
    for (int m = 32; m; m >>= 1){
        sm0 += __shfl_xor(sm0, m);
        sm1 += __shfl_xor(sm1, m);
    }
    float p0 = e0 / sm0, p1 = e1 / sm1;
    outA[((size_t)w * cB + b) * cN + n] = p0;
    outA[((size_t)(w + 4) * cB + b) * cN + n] = p1;
    // P' build: rows e*8+h, cols n, bf16 swizzled (128B rows)
    unsigned char* Pp = uB;
    bf16 bp0 = f2b(p0), bp1 = f2b(p1);
    bf16 bz = f2b(0.f);
    #pragma unroll
    for (int ee = 0; ee < cNE; ++ee){
        int r0 = ee * 8 + w, r1 = ee * 8 + w + 4;
        *(bf16*)(Pp + r0 * 128 + ((n * 2) ^ ((r0 & 7) << 4))) = (e == ee) ? bp0 : bz;
        *(bf16*)(Pp + r1 * 128 + ((n * 2) ^ ((r1 & 7) << 4))) = (e == ee) ? bp1 : bz;
    }
    __syncthreads();                       // Pp + kvT(0) ready
    char* sbg = (char*)sbuf + (size_t)b * (cEH * cDM * 2);
    #pragma unroll
    for (int hf = 0; hf < 2; ++hf){
        if (hf == 1){
            // re-stage kvT for i in [128,256) from seq_t (f32 -> bf16)
            #pragma unroll
            for (int q = 0; q < 4; ++q){
                int c = t + q * 256;
                int nn = c >> 4, il0 = (c & 15) * 8;
                float4 f0 = *(const float4*)(st_ + (size_t)nn * 512 + il0 * 4);
                float4 f1 = *(const float4*)(st_ + (size_t)nn * 512 + il0 * 4 + 16);
                bf16 hh[8];
                hh[0] = f2b(f0.x); hh[1] = f2b(f0.y); hh[2] = f2b(f0.z); hh[3] = f2b(f0.w);
                hh[4] = f2b(f1.x); hh[5] = f2b(f1.y); hh[6] = f2b(f1.z); hh[7] = f2b(f1.w);
                #pragma unroll
                for (int j = 0; j < 8; ++j){
                    int row = il0 + j;
                    *(bf16*)(kvT + row * 128 + ((nn * 2) ^ kvkey(row))) = hh[j];
                }
            }
            __syncthreads();               // kvT(1) ready
        }
        // s-MFMA: wave w owns local i-cols [32w, 32w+32); full K=64
        f32x4 sacc[3][2] = {};
        #pragma unroll
        for (int ks = 0; ks < 2; ++ks){
            int kb = ks * 64 + lg4 * 16;
            bf16x8 bfr[2];
            #pragma unroll
            for (int nt = 0; nt < 2; ++nt){
                int il = w * 32 + nt * 16 + lr;
                bfr[nt] = *(const bf16x8*)(kvT + il * 128 + (kb ^ kvkey(il)));
            }
            #pragma unroll
            for (int mt = 0; mt < 3; ++mt){
                int row = mt * 16 + lr;
                bf16x8 af = *(const bf16x8*)(Pp + row * 128 + (kb ^ ((row & 7) << 4)));
                sacc[mt][0] = __builtin_amdgcn_mfma_f32_16x16x32_bf16(af, bfr[0], sacc[mt][0], 0, 0, 0);
                sacc[mt][1] = __builtin_amdgcn_mfma_f32_16x16x32_bf16(af, bfr[1], sacc[mt][1], 0, 0, 0);
            }
        }
        __syncthreads();                   // kvT reads done -> becomes bounce buffer
        #pragma unroll
        for (int mt = 0; mt < 3; ++mt)
            #pragma unroll
            for (int nt = 0; nt < 2; ++nt)
                #pragma unroll
                for (int j = 0; j < 4; ++j){
                    int eh = mt * 16 + lg4 * 4 + j;
                    int il = w * 32 + nt * 16 + lr;
                    *(bf16*)(kvT + eh * 272 + il * 2) = f2b(sacc[mt][nt][j]);
                }
        __syncthreads();                   // bounce filled
        #pragma unroll
        for (int r = 0; r < 3; ++r){
            int c3 = t + r * 256;
            int eh = c3 >> 4, off = (c3 & 15) * 16;
            *(u32x4*)(sbg + eh * 512 + hf * 256 + off) = *(const u32x4*)(kvT + eh * 272 + off);
        }
        __syncthreads();                   // bounce drained -> region reusable
    }
}

// ------------- ovb[b, c in head h] = sum_e s[b,e,h,:] . Wv[e][c,:]  (skinny GEMM) -------------
__global__ __launch_bounds__(64) void k_sv(const bf16* __restrict__ sbuf,
        const bf16* __restrict__ Wvb, bf16* __restrict__ ovb){
    int b0 = blockIdx.x * 32, h = blockIdx.y;
    int l = threadIdx.x, lr = l & 15, lg4 = l >> 4;
    const char* sb = (const char*)sbuf;
    const char* wv = (const char*)Wvb;
    f32x4 acc[2][2] = {};
    #pragma unroll
    for (int e = 0; e < cNE; ++e){
        #pragma unroll
        for (int ks = 0; ks < 8; ++ks){
            int kb = ks * 64 + lg4 * 16;
            bf16x8 a0 = *(const bf16x8*)(sb + (size_t)(b0 + lr) * (cEH * cDM * 2) + (e * 8 + h) * 512 + kb);
            bf16x8 a1 = *(const bf16x8*)(sb + (size_t)(b0 + 16 + lr) * (cEH * cDM * 2) + (e * 8 + h) * 512 + kb);
            bf16x8 b0f = *(const bf16x8*)(wv + ((size_t)e * 256 + h * 32 + lr) * 512 + kb);
            bf16x8 b1f = *(const bf16x8*)(wv + ((size_t)e * 256 + h * 32 + 16 + lr) * 512 + kb);
            acc[0][0] = __builtin_amdgcn_mfma_f32_16x16x32_bf16(a0, b0f, acc[0][0], 0, 0, 0);
            acc[0][1] = __builtin_amdgcn_mfma_f32_16x16x32_bf16(a0, b1f, acc[0][1], 0, 0, 0);
            acc[1][0] = __builtin_amdgcn_mfma_f32_16x16x32_bf16(a1, b0f, acc[1][0], 0, 0, 0);
            acc[1][1] = __builtin_amdgcn_mfma_f32_16x16x32_bf16(a1, b1f, acc[1][1], 0, 0, 0);
        }
    }
    #pragma unroll
    for (int mt = 0; mt < 2; ++mt)
        #pragma unroll
        for (int nt = 0; nt < 2; ++nt)
            #pragma unroll
            for (int j = 0; j < 4; ++j)
                ovb[(size_t)(b0 + mt * 16 + lg4 * 4 + j) * cDM + h * 32 + nt * 16 + lr]
                    = f2b(acc[mt][nt][j]);
}

// ------------- fc (grouped by utype, MFMA) + ln3 -> catb bf16 -------------
__global__ __launch_bounds__(256) void k_fcln(const bf16* __restrict__ ovb,
        const bf16* __restrict__ fcwb, const float* __restrict__ fc_b,
        const float* __restrict__ g3, const float* __restrict__ b3,
        const int* __restrict__ ucnt, const int* __restrict__ uidx,
        const int* __restrict__ utiles, const int* __restrict__ nutiles,
        bf16* __restrict__ catb){
    __shared__ __align__(16) unsigned char Alds[32 * 512];  // 16 KB
    __shared__ int s_b[32], s_v[32];
    __shared__ float redS[32][4], redQ[32][4];
    __shared__ float s_mu[32], s_rs[32];
    if ((int)blockIdx.x >= *nutiles) return;
    int t = threadIdx.x;
    int info = utiles[blockIdx.x];
    int u = info >> 16, r0 = (info & 0xffff) * 32;
    if (t < 32){
        int cu = ucnt[u];
        int nr = min(32, cu - r0);
        s_b[t] = uidx[u * cB + ((t < nr) ? r0 + t : r0)];
        s_v[t] = (t < nr);
    }
    __syncthreads();
    #pragma unroll
    for (int i = 0; i < 4; ++i){
        int idx = t + i * 256, r = idx >> 5, ck = (idx & 31) * 16;
        u32x4 dv = *(const u32x4*)((const char*)ovb + (size_t)s_b[r] * 512 + ck);
        *(u32x4*)(Alds + r * 512 + (ck ^ ((r & 7) << 4))) = dv;
    }
    __syncthreads();
    int w = t >> 6, l = t & 63, lr = l & 15, lg4 = l >> 4;
    int colbase = w * 64, axor = (lr & 7) << 4;
    const char* WB = (const char*)(fcwb + (size_t)u * 65536);
    f32x4 acc[2][4] = {};
    #pragma unroll
    for (int ks = 0; ks < 8; ++ks){
        int kb = ks * 64 + lg4 * 16;
        bf16x8 a0 = *(const bf16x8*)(Alds + lr * 512 + (kb ^ axor));
        bf16x8 a1 = *(const bf16x8*)(Alds + (16 + lr) * 512 + (kb ^ axor));
        #pragma unroll
        for (int cf = 0; cf < 4; ++cf){
            bf16x8 bq = *(const bf16x8*)(WB + (size_t)(colbase + cf * 16 + lr) * 512 + kb);
            acc[0][cf] = __builtin_amdgcn_mfma_f32_16x16x32_bf16(a0, bq, acc[0][cf], 0, 0, 0);
            acc[1][cf] = __builtin_amdgcn_mfma_f32_16x16x32_bf16(a1, bq, acc[1][cf], 0, 0, 0);
        }
    }
    float g3v[4], b3v[4];
    #pragma unroll
    for (int cf = 0; cf < 4; ++cf){
        int col = colbase + cf * 16 + lr;
        float fb = fc_b[u * cDM + col];
        g3v[cf] = g3[col]; b3v[cf] = b3[col];
        #pragma unroll
        for (int rf = 0; rf < 2; ++rf)
            #pragma unroll
            for (int j = 0; j < 4; ++j) acc[rf][cf][j] += fb;
    }
    #pragma unroll
    for (int rf = 0; rf < 2; ++rf)
        #pragma unroll
        for (int j = 0; j < 4; ++j){
            int row = rf * 16 + lg4 * 4 + j;
            float s1 = acc[rf][0][j] + acc[rf][1][j] + acc[rf][2][j] + acc[rf][3][j];
            float s2 = acc[rf][0][j] * acc[rf][0][j] + acc[rf][1][j] * acc[rf][1][j]
                     + acc[rf][2][j] * acc[rf][2][j] + acc[rf][3][j] * acc[rf][3][j];
            #pragma unroll
            for (int m = 1; m < 16; m <<= 1){ s1 += __shfl_xor(s1, m); s2 += __shfl_xor(s2, m); }
            if (lr == 0){ redS[row][w] = s1; redQ[row][w] = s2; }
        }
    __syncthreads();
    if (t < 32){
        float s1 = redS[t][0] + redS[t][1] + redS[t][2] + redS[t][3];
        float s2 = redQ[t][0] + redQ[t][1] + redQ[t][2] + redQ[t][3];
        float mu = s1 * (1.0f / cDM);
        float var = s2 * (1.0f / cDM) - mu * mu;
        s_mu[t] = mu; s_rs[t] = rsqrtf(var + LNEPS);
    }
    __syncthreads();
    #pragma unroll
    for (int rf = 0; rf < 2; ++rf)
        #pragma unroll
        for (int j = 0; j < 4; ++j){
            int row = rf * 16 + lg4 * 4 + j;
            if (!s_v[row]) continue;
            size_t bofs = (size_t)s_b[row] * cDM;
            float mu = s_mu[row], rs = s_rs[row];
            #pragma unroll
            for (int cf = 0; cf < 4; ++cf){
                int col = colbase + cf * 16 + lr;
                catb[bofs + col] = f2b((acc[rf][cf][j] - mu) * rs * g3v[cf] + b3v[cf]);
            }
        }
}

// ------------- dense MLP: hmid = relu([cat,src] @ m1w.T + m1b); out = hmid @ m2w.T + m2b -------------
__global__ __launch_bounds__(256) void k_mlp(const bf16* __restrict__ catb,
        const bf16* __restrict__ srcb, const bf16* __restrict__ m1wb,
        const float* __restrict__ m1b, const bf16* __restrict__ m2wb,
        const float* __restrict__ m2b, float* __restrict__ outF){
    __shared__ __align__(16) unsigned char Alds[16 * 768];  // 12 KB
    __shared__ __align__(16) unsigned char Hlds[16 * 256];  // 4 KB
    int t = threadIdx.x;
    int b0 = blockIdx.x * 16;
    #pragma unroll
    for (int i = 0; i < 3; ++i){
        int idx = t + i * 256;
        int r = idx / 48, c = idx - r * 48;
        const char* sp = (c < 32)
            ? (const char*)catb + (size_t)(b0 + r) * 512 + c * 16
            : (const char*)srcb + (size_t)(b0 + r) * 256 + (c - 32) * 16;
        *(u32x4*)(Alds + r * 768 + ((c * 16) ^ ((r & 7) << 4))) = *(const u32x4*)sp;
    }
    __syncthreads();
    int w = t >> 6, l = t & 63, lr = l & 15, lg4 = l >> 4;
    int colbase = w * 32, axor = (lr & 7) << 4;
    f32x4 acc[2] = {};
    #pragma unroll
    for (int ks = 0; ks < 12; ++ks){
        int kb = ks * 64 + lg4 * 16;
        bf16x8 a0 = *(const bf16x8*)(Alds + lr * 768 + (kb ^ axor));
        #pragma unroll
        for (int cf = 0; cf < 2; ++cf){
            bf16x8 bq = *(const bf16x8*)((const char*)m1wb + (size_t)(colbase + cf * 16 + lr) * 768 + kb);
            acc[cf] = __builtin_amdgcn_mfma_f32_16x16x32_bf16(a0, bq, acc[cf], 0, 0, 0);
        }
    }
    #pragma unroll
    for (int cf = 0; cf < 2; ++cf){
        int col = colbase + cf * 16 + lr;
        float mb = m1b[col];
        #pragma unroll
        for (int j = 0; j < 4; ++j){
            int row = lg4 * 4 + j;
            float v = fmaxf(acc[cf][j] + mb, 0.f);
            *(bf16*)(Hlds + row * 256 + ((col * 2) ^ ((row & 7) << 4))) = f2b(v);
        }
    }
    __syncthreads();
    f32x4 acc2[2] = {};
    #pragma unroll
    for (int ks = 0; ks < 4; ++ks){
        int kb = ks * 64 + lg4 * 16;
        bf16x8 a0 = *(const bf16x8*)(Hlds + lr * 256 + (kb ^ axor));
        #pragma unroll
        for (int cf = 0; cf < 2; ++cf){
            bf16x8 bq = *(const bf16x8*)((const char*)m2wb + (size_t)(colbase + cf * 16 + lr) * 256 + kb);
            acc2[cf] = __builtin_amdgcn_mfma_f32_16x16x32_bf16(a0, bq, acc2[cf], 0, 0, 0);
        }
    }
    #pragma unroll
    for (int cf = 0; cf < 2; ++cf){
        int col = colbase + cf * 16 + lr;
        float mb = m2b[col];
        #pragma unroll
        for (int j = 0; j < 4; ++j){
            int row = lg4 * 4 + j;
            outF[(size_t)(b0 + row) * cD + col] = acc2[cf][j] + mb;
        }
    }
}

extern "C" void kernel_launch(void* const* d_in, const int* in_sizes, int n_in,
                              void* d_out, int out_size, void* d_ws, size_t ws_size,
                              hipStream_t stream) {
    const float* src    = (const float*)d_in[0];
    const float* src_t  = (const float*)d_in[1];
    const float* seq    = (const float*)d_in[2];
    const float* seq_t  = (const float*)d_in[3];
    const float* seq_e  = (const float*)d_in[4];
    const float* Wq     = (const float*)d_in[5];
    const float* Wk     = (const float*)d_in[6];
    const float* Wv     = (const float*)d_in[7];
    const float* rpri   = (const float*)d_in[8];
    const float* fc_w   = (const float*)d_in[9];
    const float* fc_b   = (const float*)d_in[10];
    const float* ln1g   = (const float*)d_in[11];
    const float* ln1b   = (const float*)d_in[12];
    const float* ln2g   = (const float*)d_in[13];
    const float* ln2b   = (const float*)d_in[14];
    const float* ln3g   = (const float*)d_in[15];
    const float* ln3b   = (const float*)d_in[16];
    const float* m1w    = (const float*)d_in[17];
    const float* m1b    = (const float*)d_in[18];
    const float* m2w    = (const float*)d_in[19];
    const float* m2b    = (const float*)d_in[20];
    const int*  etype   = (const int*)d_in[21];
    const int*  utype   = (const int*)d_in[22];
    const int*  maskp   = (const int*)d_in[24];

    // workspace layout (bf16 regions, then ints)
    bf16*  qcatb  = (bf16*)d_ws;                           // B*DM
    bf16*  kvecL  = qcatb + (size_t)cB * cDM;              // BN*D (LN half only)
    bf16*  Wqb    = kvecL + (size_t)cBN * cD;              // NE*DM*DM
    bf16*  Wvb    = Wqb + (size_t)cNE * cDM * cDM;         // NE*DM*DM
    bf16*  WkT    = Wvb + (size_t)cNE * cDM * cDM;         // NE*DM*DM
    bf16*  Qeb    = WkT + (size_t)cNE * cDM * cDM;         // B*NE*DM
    bf16*  qk     = Qeb + (size_t)cB * cNE * cDM;          // B*NE*H*DM
    bf16*  sbuf   = qk + (size_t)cB * cNE * cH * cDM;      // B*EH*DM
    bf16*  ovb    = sbuf + (size_t)cB * cEH * cDM;         // B*DM
    bf16*  catb   = ovb + (size_t)cB * cDM;                // B*DM
    bf16*  srcb   = catb + (size_t)cB * cDM;               // B*D
    bf16*  fcwb   = srcb + (size_t)cB * cD;                // NU*DM*DM
    bf16*  m1wb   = fcwb + (size_t)cNU * cDM * cDM;        // D*(DM+D)
    bf16*  m2wb   = m1wb + (size_t)cD * (cDM + cD);        // D*D
    int*   ucnt   = (int*)(m2wb + (size_t)cD * cD);        // 4
    int*   uidx   = ucnt + 4;                              // NU*B
    int*   utiles = uidx + (size_t)cNU * cB;               // MAXUT
    int*   nutiles= utiles + MAXUT;                        // 1

    float* outF = (float*)d_out;
    float* outA = outF + (size_t)cB * cD;

    k_wprep<<<dim3(384, 6), dim3(256), 0, stream>>>(Wq, Wk, Wv, fc_w, m1w, m2w,
                                                    Wqb, Wvb, WkT, fcwb, m1wb, m2wb);
    k_qprep<<<dim3(cB / 4), dim3(256), 0, stream>>>(src, src_t, ln1g, ln1b, qcatb, srcb);
    k_ln<<<dim3(cBN / 8), dim3(256), 0, stream>>>(seq, seq_e, ln2g, ln2b, kvecL);
    k_uprep<<<dim3(1), dim3(256), 0, stream>>>(utype, ucnt, uidx, utiles, nutiles);
    k_gemmQ<<<dim3(cB / 32, cNE), dim3(256), 0, stream>>>(qcatb, Wqb, Qeb);
    k_qk<<<dim3(cB / 32, cNE, cH), dim3(256), 0, stream>>>(Qeb, WkT, rpri, utype, qk);
    k_attn<<<dim3(cB), dim3(256), 0, stream>>>(kvecL, seq_t, qk, etype, maskp, outA, sbuf);
    k_sv<<<dim3(cB / 32, cH), dim3(64), 0, stream>>>(sbuf, Wvb, ovb);
    k_fcln<<<dim3(MAXUT), dim3(256), 0, stream>>>(ovb, fcwb, fc_b, ln3g, ln3b,
                                                  ucnt, uidx, utiles, nutiles, catb);
    k_mlp<<<dim3(cB / 16), dim3(256), 0, stream>>>(catb, srcb, m1wb, m1b, m2wb, m2b, outF);
}

// Round 17
// 172.652 us; speedup vs baseline: 1.1280x; 1.1280x over previous
//
#include <hip/hip_runtime.h>
#include <hip/hip_bf16.h>

typedef __hip_bfloat16 bf16;
typedef __attribute__((ext_vector_type(8))) __bf16 bf16x8;
typedef __attribute__((ext_vector_type(4))) float f32x4;
typedef __attribute__((ext_vector_type(4))) unsigned int u32x4;

static __device__ __forceinline__ float b2f(bf16 x){ return __bfloat162float(x); }
static __device__ __forceinline__ bf16  f2b(float x){ return __float2bfloat16(x); }

constexpr int cB = 2048, cN = 64, cD = 128, cDM = 256, cH = 8, cNE = 6, cNU = 4;
constexpr int cBN = cB * cN;                 // 131072 rows
constexpr float LNEPS = 1e-5f;
constexpr float RSQ32 = 0.17677669529663687f; // 1/sqrt(32)
constexpr int MAXUT = 80;                     // >= 2048/32 + 4
constexpr int cEH = cNE * cH;                 // 48

// kvT swizzle key: varies with BOTH i&7 and (i>>3)&7 (needed so register-staging
// writes from the 4 lg4 groups land in distinct 16B slots -> <=2-way).
static __device__ __forceinline__ int kvkey(int row){ return ((row ^ (row >> 3)) & 7) << 4; }

// ------------- fused weight prep: Wq/Wv/fc/m1/m2 bf16 convert, Wk transpose -------------
__global__ __launch_bounds__(256) void k_wprep(const float* __restrict__ Wq,
        const float* __restrict__ Wk, const float* __restrict__ Wv,
        const float* __restrict__ fc_w, const float* __restrict__ m1w,
        const float* __restrict__ m2w,
        bf16* __restrict__ Wqb, bf16* __restrict__ Wvb, bf16* __restrict__ WkT,
        bf16* __restrict__ fcwb, bf16* __restrict__ m1wb, bf16* __restrict__ m2wb){
    __shared__ bf16 tile[32][33];
    int y = blockIdx.y, x = blockIdx.x, t = threadIdx.x;
    if (y == 5){
        int e = x >> 6, tb = x & 63;
        int tr = tb >> 3, tc = tb & 7;
        int r = t >> 3, c4 = (t & 7) * 4;
        float4 v = *(const float4*)(Wk + ((size_t)e * 256 + tr * 32 + r) * 256 + tc * 32 + c4);
        tile[r][c4 + 0] = f2b(v.x); tile[r][c4 + 1] = f2b(v.y);
        tile[r][c4 + 2] = f2b(v.z); tile[r][c4 + 3] = f2b(v.w);
        __syncthreads();
        union { bf16 h[4]; uint2 u; } p;
        p.h[0] = tile[c4 + 0][r]; p.h[1] = tile[c4 + 1][r];
        p.h[2] = tile[c4 + 2][r]; p.h[3] = tile[c4 + 3][r];
        *(uint2*)&WkT[((size_t)e * 256 + tc * 32 + r) * 256 + tr * 32 + c4] = p.u;
        return;
    }
    const float* s; bf16* d; int n4;
    switch (y){
        case 0: s = Wq;   d = Wqb;  n4 = cNE * cDM * cDM / 4; break;
        case 1: s = Wv;   d = Wvb;  n4 = cNE * cDM * cDM / 4; break;
        case 2: s = fc_w; d = fcwb; n4 = cNU * cDM * cDM / 4; break;
        case 3: s = m1w;  d = m1wb; n4 = cD * (cDM + cD) / 4; break;
        default: s = m2w; d = m2wb; n4 = cD * cD / 4; break;
    }
    int i = x * 256 + t;
    if (i >= n4) return;
    float4 v = ((const float4*)s)[i];
    union { bf16 h[4]; uint2 u; } p;
    p.h[0] = f2b(v.x); p.h[1] = f2b(v.y); p.h[2] = f2b(v.z); p.h[3] = f2b(v.w);
    *(uint2*)&d[(size_t)i * 4] = p.u;
}

// ---------------- qcatb[b] = bf16([ln1(src[b]), src_t[b]]); srcb = bf16(src) ----------------
__global__ __launch_bounds__(256) void k_qprep(const float* __restrict__ src,
        const float* __restrict__ src_t, const float* __restrict__ g1,
        const float* __restrict__ b1, bf16* __restrict__ qcatb,
        bf16* __restrict__ srcb){
    int lane = threadIdx.x & 63;
    int b = blockIdx.x * 4 + (threadIdx.x >> 6);
    const float* s = src + b * cD;
    float x0 = s[lane], x1 = s[lane + 64];
    srcb[b * cD + lane]      = f2b(x0);
    srcb[b * cD + lane + 64] = f2b(x1);
    float sm = x0 + x1;
    #pragma unroll
    for (int m = 32; m; m >>= 1) sm += __shfl_xor(sm, m);
    float mu = sm * (1.0f / cD);
    float d0 = x0 - mu, d1 = x1 - mu;
    float vs = d0 * d0 + d1 * d1;
    #pragma unroll
    for (int m = 32; m; m >>= 1) vs += __shfl_xor(vs, m);
    float rs = rsqrtf(vs * (1.0f / cD) + LNEPS);
    bf16* q = qcatb + b * cDM;
    q[lane]        = f2b(d0 * rs * g1[lane] + b1[lane]);
    q[lane + 64]   = f2b(d1 * rs * g1[lane + 64] + b1[lane + 64]);
    q[cD + lane]      = f2b(src_t[b * cD + lane]);
    q[cD + lane + 64] = f2b(src_t[b * cD + lane + 64]);
}

// ------------- k_ln: kvecL[row][0:128] = bf16(ln2(seq+seq_e))  (256B rows) -------------
__global__ __launch_bounds__(256) void k_ln(const float* __restrict__ seq,
        const float* __restrict__ seq_e, const float* __restrict__ g2,
        const float* __restrict__ b2v, bf16* __restrict__ kvecL){
    int t = threadIdx.x;
    int l = t & 31, g = t >> 5;
    int row = blockIdx.x * 8 + g;
    float4 a  = *(const float4*)(seq   + (size_t)row * cD + l * 4);
    float4 eV = *(const float4*)(seq_e + (size_t)row * cD + l * 4);
    float x[4] = {a.x + eV.x, a.y + eV.y, a.z + eV.z, a.w + eV.w};
    float sm = (x[0] + x[1]) + (x[2] + x[3]);
    #pragma unroll
    for (int m = 16; m; m >>= 1) sm += __shfl_xor(sm, m);
    float mu = sm * (1.0f / cD), vs = 0.f;
    #pragma unroll
    for (int j = 0; j < 4; ++j){ x[j] -= mu; vs += x[j] * x[j]; }
    #pragma unroll
    for (int m = 16; m; m >>= 1) vs += __shfl_xor(vs, m);
    float rs = rsqrtf(vs * (1.0f / cD) + LNEPS);
    float4 gg = *(const float4*)(g2 + l * 4);
    float4 bb = *(const float4*)(b2v + l * 4);
    union { bf16 h[4]; uint2 u; } p;
    p.h[0] = f2b(x[0] * rs * gg.x + bb.x);
    p.h[1] = f2b(x[1] * rs * gg.y + bb.y);
    p.h[2] = f2b(x[2] * rs * gg.z + bb.z);
    p.h[3] = f2b(x[3] * rs * gg.w + bb.w);
    *(uint2*)&kvecL[(size_t)row * cD + l * 4] = p.u;
}

// ------------- utype gather: counts, index lists, tile list (single block) -------------
__global__ __launch_bounds__(256) void k_uprep(const int* __restrict__ utype,
        int* __restrict__ ucnt, int* __restrict__ uidx,
        int* __restrict__ utiles, int* __restrict__ nutiles){
    __shared__ int lc[cNU], cur[cNU];
    int t = threadIdx.x;
    if (t < cNU){ lc[t] = 0; cur[t] = 0; }
    __syncthreads();
    #pragma unroll
    for (int i = 0; i < 8; ++i) atomicAdd(&lc[utype[t + i * 256]], 1);
    __syncthreads();
    if (t < cNU) ucnt[t] = lc[t];
    #pragma unroll
    for (int i = 0; i < 8; ++i){
        int b = t + i * 256;
        int u = utype[b];
        int pos = atomicAdd(&cur[u], 1);
        uidx[u * cB + pos] = b;
    }
    __syncthreads();
    if (t == 0){
        int s = 0;
        for (int u = 0; u < cNU; ++u){
            int nt = (lc[u] + 31) >> 5;
            for (int k = 0; k < nt; ++k) utiles[s + k] = (u << 16) | k;
            s += nt;
        }
        *nutiles = s;
    }
}

// ------------- Qeb[b][e] = bf16(qcat[b] @ Wq[e].T) via MFMA -------------
__global__ __launch_bounds__(256) void k_gemmQ(const bf16* __restrict__ qcatb,
        const bf16* __restrict__ Wqb, bf16* __restrict__ Qeb){
    int t = threadIdx.x, w = t >> 6, l = t & 63;
    int lr = l & 15, lg4 = l >> 4;
    int b0 = blockIdx.x * 32, e = blockIdx.y;
    const char* A  = (const char*)qcatb + (size_t)b0 * 512;
    const char* Wq = (const char*)(Wqb + (size_t)e * 65536);
    int colbase = w * 64;
    f32x4 acc[2][4] = {};
    #pragma unroll
    for (int ks = 0; ks < 8; ++ks){
        int kb = ks * 64 + lg4 * 16;
        bf16x8 a0 = *(const bf16x8*)(A + (size_t)lr * 512 + kb);
        bf16x8 a1 = *(const bf16x8*)(A + (size_t)(16 + lr) * 512 + kb);
        #pragma unroll
        for (int cf = 0; cf < 4; ++cf){
            bf16x8 bq = *(const bf16x8*)(Wq + (size_t)(colbase + cf * 16 + lr) * 512 + kb);
            acc[0][cf] = __builtin_amdgcn_mfma_f32_16x16x32_bf16(a0, bq, acc[0][cf], 0, 0, 0);
            acc[1][cf] = __builtin_amdgcn_mfma_f32_16x16x32_bf16(a1, bq, acc[1][cf], 0, 0, 0);
        }
    }
    #pragma unroll
    for (int rf = 0; rf < 2; ++rf)
        #pragma unroll
        for (int cf = 0; cf < 4; ++cf)
            #pragma unroll
            for (int j = 0; j < 4; ++j){
                int b = b0 + rf * 16 + lg4 * 4 + j;
                Qeb[((size_t)b * cNE + e) * cDM + colbase + cf * 16 + lr] = f2b(acc[rf][cf][j]);
            }
}

// ------------- qk[b][e][h][:] = (pri/sqrt(32)) * (Qe[b,e,head h] @ Wk[e][head h, :]) -------------
__global__ __launch_bounds__(256) void k_qk(const bf16* __restrict__ Qeb,
        const bf16* __restrict__ WkT, const float* __restrict__ rpri,
        const int* __restrict__ utype, bf16* __restrict__ qk){
    __shared__ float s_pri[32];
    int t = threadIdx.x, w = t >> 6, l = t & 63;
    int lr = l & 15, lg4 = l >> 4;
    int b0 = blockIdx.x * 32, e = blockIdx.y, h = blockIdx.z;
    if (t < 32) s_pri[t] = rpri[utype[b0 + t] * cNE + e] * RSQ32;
    __syncthreads();
    int colbase = w * 64;
    bf16x8 a0 = *(const bf16x8*)(Qeb + ((size_t)(b0 + lr) * cNE + e) * cDM + h * 32 + lg4 * 8);
    bf16x8 a1 = *(const bf16x8*)(Qeb + ((size_t)(b0 + 16 + lr) * cNE + e) * cDM + h * 32 + lg4 * 8);
    f32x4 acc[2][4] = {};
    #pragma unroll
    for (int cf = 0; cf < 4; ++cf){
        bf16x8 bq = *(const bf16x8*)(WkT + ((size_t)e * 256 + colbase + cf * 16 + lr) * 256 + h * 32 + lg4 * 8);
        acc[0][cf] = __builtin_amdgcn_mfma_f32_16x16x32_bf16(a0, bq, acc[0][cf], 0, 0, 0);
        acc[1][cf] = __builtin_amdgcn_mfma_f32_16x16x32_bf16(a1, bq, acc[1][cf], 0, 0, 0);
    }
    #pragma unroll
    for (int rf = 0; rf < 2; ++rf)
        #pragma unroll
        for (int cf = 0; cf < 4; ++cf)
            #pragma unroll
            for (int j = 0; j < 4; ++j){
                int bb = b0 + rf * 16 + lg4 * 4 + j;
                float sc = s_pri[rf * 16 + lg4 * 4 + j];
                qk[(((size_t)bb * cNE + e) * cH + h) * cDM + colbase + cf * 16 + lr]
                    = f2b(acc[rf][cf][j] * sc);
            }
}

// ------------- per-b: logits MFMA (A-frags kept in regs), softmax, s = P'@kv -------------
// Single-read: kvecL and seq_t are each read ONCE (as logits A-frags); kvT is staged
// from those registers. No global re-reads for the s-GEMM.
__global__ __launch_bounds__(256, 4) void k_attn(const bf16* __restrict__ kvecL,
        const float* __restrict__ seq_t, const bf16* __restrict__ qk,
        const int* __restrict__ etype, const int* __restrict__ maskp,
        float* __restrict__ outA, bf16* __restrict__ sbuf){
    __shared__ __align__(16) unsigned char kvT[16384];
    __shared__ __align__(16) unsigned char uB[64 * 49 * 4];
    __shared__ int s_e[cN], s_m[cN];
    int b = blockIdx.x, t = threadIdx.x;
    if (t < cN){ s_e[t] = etype[b * cN + t]; s_m[t] = maskp[b * cN + t]; }
    int w = t >> 6, l = t & 63, lr = l & 15, lg4 = l >> 4;
    int an = w * 16 + lr;                  // this thread's A-row (n index)
    const char* kl_ = (const char*)(kvecL + (size_t)b * cN * cD);   // 256B rows
    const char* st_ = (const char*)(seq_t + (size_t)b * cN * cD);   // 512B rows (f32)
    const char* Arow = kl_ + (size_t)an * 256;
    const char* Ast  = st_ + (size_t)an * 512;
    const char* Bq = (const char*)(qk + (size_t)b * (cNE * cH * cDM));
    bf16x8 afk[8];                         // A-frags, kept for kvT staging
    f32x4 acc[3] = {};
    #pragma unroll
    for (int ks = 0; ks < 4; ++ks){
        int kb = ks * 64 + lg4 * 16;
        afk[ks] = *(const bf16x8*)(Arow + kb);
        #pragma unroll
        for (int cf = 0; cf < 3; ++cf){
            bf16x8 bq = *(const bf16x8*)(Bq + (size_t)(cf * 16 + lr) * 512 + kb);
            acc[cf] = __builtin_amdgcn_mfma_f32_16x16x32_bf16(afk[ks], bq, acc[cf], 0, 0, 0);
        }
    }
    #pragma unroll
    for (int ks = 4; ks < 8; ++ks){
        int kb = ks * 64 + lg4 * 16;
        float4 f0 = *(const float4*)(Ast + kb * 2 - 512);
        float4 f1 = *(const float4*)(Ast + kb * 2 - 496);
        union { bf16x8 v; bf16 hh[8]; } ua;
        ua.hh[0] = f2b(f0.x); ua.hh[1] = f2b(f0.y); ua.hh[2] = f2b(f0.z); ua.hh[3] = f2b(f0.w);
        ua.hh[4] = f2b(f1.x); ua.hh[5] = f2b(f1.y); ua.hh[6] = f2b(f1.z); ua.hh[7] = f2b(f1.w);
        afk[ks] = ua.v;
        #pragma unroll
        for (int cf = 0; cf < 3; ++cf){
            bf16x8 bq = *(const bf16x8*)(Bq + (size_t)(cf * 16 + lr) * 512 + kb);
            acc[cf] = __builtin_amdgcn_mfma_f32_16x16x32_bf16(afk[ks], bq, acc[cf], 0, 0, 0);
        }
    }
    float* lgAll = (float*)uB;
    #pragma unroll
    for (int cf = 0; cf < 3; ++cf)
        #pragma unroll
        for (int j = 0; j < 4; ++j)
            lgAll[(w * 16 + lg4 * 4 + j) * 49 + cf * 16 + lr] = acc[cf][j];
    __syncthreads();                       // lgAll + s_e ready
    // softmax: wave w handles heads w and w+4; lane l == n
    int n = l;
    int e = s_e[n];
    bool msk = s_m[n] != 0;
    float v0 = msk ? -1e10f : lgAll[n * 49 + e * 8 + w];
    float v1 = msk ? -1e10f : lgAll[n * 49 + e * 8 + w + 4];
    __syncthreads();                       // lgAll dead; uB becomes Pp
    float m0 = v0, m1v = v1;
    #pragma unroll
    for (int m = 32; m; m >>= 1){
        m0 = fmaxf(m0, __shfl_xor(m0, m));
        m1v = fmaxf(m1v, __shfl_xor(m1v, m));
    }
    float e0 = expf(v0 - m0), e1 = expf(v1 - m1v);
    float sm0 = e0, sm1 = e1;
    #pragma unroll
    for (int m = 32; m; m >>= 1){
        sm0 += __shfl_xor(sm0, m);
        sm1 += __shfl_xor(sm1, m);
    }
    float p0 = e0 / sm0, p1 = e1 / sm1;
    outA[((size_t)w * cB + b) * cN + n] = p0;
    outA[((size_t)(w + 4) * cB + b) * cN + n] = p1;
    // P' build: rows e*8+h, cols n, bf16 swizzled (128B rows)
    unsigned char* Pp = uB;
    bf16 bp0 = f2b(p0), bp1 = f2b(p1);
    bf16 bz = f2b(0.f);
    #pragma unroll
    for (int ee = 0; ee < cNE; ++ee){
        int r0 = ee * 8 + w, r1 = ee * 8 + w + 4;
        *(bf16*)(Pp + r0 * 128 + ((n * 2) ^ ((r0 & 7) << 4))) = (e == ee) ? bp0 : bz;
        *(bf16*)(Pp + r1 * 128 + ((n * 2) ^ ((r1 & 7) << 4))) = (e == ee) ? bp1 : bz;
    }
    // stage kvT(0) from afk[0..3] registers (conflict <=2-way via kvkey)
    #pragma unroll
    for (int ks = 0; ks < 4; ++ks){
        union { bf16x8 v; bf16 hh[8]; } ua; ua.v = afk[ks];
        int i0 = ks * 32 + lg4 * 8;
        #pragma unroll
        for (int j = 0; j < 8; ++j){
            int row = i0 + j;
            *(bf16*)(kvT + row * 128 + ((an * 2) ^ kvkey(row))) = ua.hh[j];
        }
    }
    __syncthreads();                       // Pp + kvT(0) ready
    char* sbg = (char*)sbuf + (size_t)b * (cEH * cDM * 2);
    #pragma unroll
    for (int hf = 0; hf < 2; ++hf){
        if (hf == 1){
            // stage kvT(1) from afk[4..7] registers (no global reads)
            #pragma unroll
            for (int ks = 4; ks < 8; ++ks){
                union { bf16x8 v; bf16 hh[8]; } ua; ua.v = afk[ks];
                int i0 = (ks - 4) * 32 + lg4 * 8;
                #pragma unroll
                for (int j = 0; j < 8; ++j){
                    int row = i0 + j;
                    *(bf16*)(kvT + row * 128 + ((an * 2) ^ kvkey(row))) = ua.hh[j];
                }
            }
            __syncthreads();               // kvT(1) ready
        }
        // s-MFMA: wave w owns local i-cols [32w, 32w+32); full K=64
        f32x4 sacc[3][2] = {};
        #pragma unroll
        for (int ks = 0; ks < 2; ++ks){
            int kb = ks * 64 + lg4 * 16;
            bf16x8 bfr[2];
            #pragma unroll
            for (int nt = 0; nt < 2; ++nt){
                int il = w * 32 + nt * 16 + lr;
                bfr[nt] = *(const bf16x8*)(kvT + il * 128 + (kb ^ kvkey(il)));
            }
            #pragma unroll
            for (int mt = 0; mt < 3; ++mt){
                int row = mt * 16 + lr;
                bf16x8 af = *(const bf16x8*)(Pp + row * 128 + (kb ^ ((row & 7) << 4)));
                sacc[mt][0] = __builtin_amdgcn_mfma_f32_16x16x32_bf16(af, bfr[0], sacc[mt][0], 0, 0, 0);
                sacc[mt][1] = __builtin_amdgcn_mfma_f32_16x16x32_bf16(af, bfr[1], sacc[mt][1], 0, 0, 0);
            }
        }
        __syncthreads();                   // kvT reads done -> becomes bounce buffer
        #pragma unroll
        for (int mt = 0; mt < 3; ++mt)
            #pragma unroll
            for (int nt = 0; nt < 2; ++nt)
                #pragma unroll
                for (int j = 0; j < 4; ++j){
                    int eh = mt * 16 + lg4 * 4 + j;
                    int il = w * 32 + nt * 16 + lr;
                    *(bf16*)(kvT + eh * 272 + il * 2) = f2b(sacc[mt][nt][j]);
                }
        __syncthreads();                   // bounce filled
        #pragma unroll
        for (int r = 0; r < 3; ++r){
            int c3 = t + r * 256;
            int eh = c3 >> 4, off = (c3 & 15) * 16;
            *(u32x4*)(sbg + eh * 512 + hf * 256 + off) = *(const u32x4*)(kvT + eh * 272 + off);
        }
        __syncthreads();                   // bounce drained -> region reusable
    }
}

// ------------- ovb[b, c in head h] = sum_e s[b,e,h,:] . Wv[e][c,:]  (skinny GEMM) -------------
__global__ __launch_bounds__(64) void k_sv(const bf16* __restrict__ sbuf,
        const bf16* __restrict__ Wvb, bf16* __restrict__ ovb){
    int b0 = blockIdx.x * 32, h = blockIdx.y;
    int l = threadIdx.x, lr = l & 15, lg4 = l >> 4;
    const char* sb = (const char*)sbuf;
    const char* wv = (const char*)Wvb;
    f32x4 acc[2][2] = {};
    #pragma unroll
    for (int e = 0; e < cNE; ++e){
        #pragma unroll
        for (int ks = 0; ks < 8; ++ks){
            int kb = ks * 64 + lg4 * 16;
            bf16x8 a0 = *(const bf16x8*)(sb + (size_t)(b0 + lr) * (cEH * cDM * 2) + (e * 8 + h) * 512 + kb);
            bf16x8 a1 = *(const bf16x8*)(sb + (size_t)(b0 + 16 + lr) * (cEH * cDM * 2) + (e * 8 + h) * 512 + kb);
            bf16x8 b0f = *(const bf16x8*)(wv + ((size_t)e * 256 + h * 32 + lr) * 512 + kb);
            bf16x8 b1f = *(const bf16x8*)(wv + ((size_t)e * 256 + h * 32 + 16 + lr) * 512 + kb);
            acc[0][0] = __builtin_amdgcn_mfma_f32_16x16x32_bf16(a0, b0f, acc[0][0], 0, 0, 0);
            acc[0][1] = __builtin_amdgcn_mfma_f32_16x16x32_bf16(a0, b1f, acc[0][1], 0, 0, 0);
            acc[1][0] = __builtin_amdgcn_mfma_f32_16x16x32_bf16(a1, b0f, acc[1][0], 0, 0, 0);
            acc[1][1] = __builtin_amdgcn_mfma_f32_16x16x32_bf16(a1, b1f, acc[1][1], 0, 0, 0);
        }
    }
    #pragma unroll
    for (int mt = 0; mt < 2; ++mt)
        #pragma unroll
        for (int nt = 0; nt < 2; ++nt)
            #pragma unroll
            for (int j = 0; j < 4; ++j)
                ovb[(size_t)(b0 + mt * 16 + lg4 * 4 + j) * cDM + h * 32 + nt * 16 + lr]
                    = f2b(acc[mt][nt][j]);
}

// ------------- fc (grouped by utype, MFMA) + ln3 -> catb bf16 -------------
__global__ __launch_bounds__(256) void k_fcln(const bf16* __restrict__ ovb,
        const bf16* __restrict__ fcwb, const float* __restrict__ fc_b,
        const float* __restrict__ g3, const float* __restrict__ b3,
        const int* __restrict__ ucnt, const int* __restrict__ uidx,
        const int* __restrict__ utiles, const int* __restrict__ nutiles,
        bf16* __restrict__ catb){
    __shared__ __align__(16) unsigned char Alds[32 * 512];  // 16 KB
    __shared__ int s_b[32], s_v[32];
    __shared__ float redS[32][4], redQ[32][4];
    __shared__ float s_mu[32], s_rs[32];
    if ((int)blockIdx.x >= *nutiles) return;
    int t = threadIdx.x;
    int info = utiles[blockIdx.x];
    int u = info >> 16, r0 = (info & 0xffff) * 32;
    if (t < 32){
        int cu = ucnt[u];
        int nr = min(32, cu - r0);
        s_b[t] = uidx[u * cB + ((t < nr) ? r0 + t : r0)];
        s_v[t] = (t < nr);
    }
    __syncthreads();
    #pragma unroll
    for (int i = 0; i < 4; ++i){
        int idx = t + i * 256, r = idx >> 5, ck = (idx & 31) * 16;
        u32x4 dv = *(const u32x4*)((const char*)ovb + (size_t)s_b[r] * 512 + ck);
        *(u32x4*)(Alds + r * 512 + (ck ^ ((r & 7) << 4))) = dv;
    }
    __syncthreads();
    int w = t >> 6, l = t & 63, lr = l & 15, lg4 = l >> 4;
    int colbase = w * 64, axor = (lr & 7) << 4;
    const char* WB = (const char*)(fcwb + (size_t)u * 65536);
    f32x4 acc[2][4] = {};
    #pragma unroll
    for (int ks = 0; ks < 8; ++ks){
        int kb = ks * 64 + lg4 * 16;
        bf16x8 a0 = *(const bf16x8*)(Alds + lr * 512 + (kb ^ axor));
        bf16x8 a1 = *(const bf16x8*)(Alds + (16 + lr) * 512 + (kb ^ axor));
        #pragma unroll
        for (int cf = 0; cf < 4; ++cf){
            bf16x8 bq = *(const bf16x8*)(WB + (size_t)(colbase + cf * 16 + lr) * 512 + kb);
            acc[0][cf] = __builtin_amdgcn_mfma_f32_16x16x32_bf16(a0, bq, acc[0][cf], 0, 0, 0);
            acc[1][cf] = __builtin_amdgcn_mfma_f32_16x16x32_bf16(a1, bq, acc[1][cf], 0, 0, 0);
        }
    }
    float g3v[4], b3v[4];
    #pragma unroll
    for (int cf = 0; cf < 4; ++cf){
        int col = colbase + cf * 16 + lr;
        float fb = fc_b[u * cDM + col];
        g3v[cf] = g3[col]; b3v[cf] = b3[col];
        #pragma unroll
        for (int rf = 0; rf < 2; ++rf)
            #pragma unroll
            for (int j = 0; j < 4; ++j) acc[rf][cf][j] += fb;
    }
    #pragma unroll
    for (int rf = 0; rf < 2; ++rf)
        #pragma unroll
        for (int j = 0; j < 4; ++j){
            int row = rf * 16 + lg4 * 4 + j;
            float s1 = acc[rf][0][j] + acc[rf][1][j] + acc[rf][2][j] + acc[rf][3][j];
            float s2 = acc[rf][0][j] * acc[rf][0][j] + acc[rf][1][j] * acc[rf][1][j]
                     + acc[rf][2][j] * acc[rf][2][j] + acc[rf][3][j] * acc[rf][3][j];
            #pragma unroll
            for (int m = 1; m < 16; m <<= 1){ s1 += __shfl_xor(s1, m); s2 += __shfl_xor(s2, m); }
            if (lr == 0){ redS[row][w] = s1; redQ[row][w] = s2; }
        }
    __syncthreads();
    if (t < 32){
        float s1 = redS[t][0] + redS[t][1] + redS[t][2] + redS[t][3];
        float s2 = redQ[t][0] + redQ[t][1] + redQ[t][2] + redQ[t][3];
        float mu = s1 * (1.0f / cDM);
        float var = s2 * (1.0f / cDM) - mu * mu;
        s_mu[t] = mu; s_rs[t] = rsqrtf(var + LNEPS);
    }
    __syncthreads();
    #pragma unroll
    for (int rf = 0; rf < 2; ++rf)
        #pragma unroll
        for (int j = 0; j < 4; ++j){
            int row = rf * 16 + lg4 * 4 + j;
            if (!s_v[row]) continue;
            size_t bofs = (size_t)s_b[row] * cDM;
            float mu = s_mu[row], rs = s_rs[row];
            #pragma unroll
            for (int cf = 0; cf < 4; ++cf){
                int col = colbase + cf * 16 + lr;
                catb[bofs + col] = f2b((acc[rf][cf][j] - mu) * rs * g3v[cf] + b3v[cf]);
            }
        }
}

// ------------- dense MLP: hmid = relu([cat,src] @ m1w.T + m1b); out = hmid @ m2w.T + m2b -------------
__global__ __launch_bounds__(256) void k_mlp(const bf16* __restrict__ catb,
        const bf16* __restrict__ srcb, const bf16* __restrict__ m1wb,
        const float* __restrict__ m1b, const bf16* __restrict__ m2wb,
        const float* __restrict__ m2b, float* __restrict__ outF){
    __shared__ __align__(16) unsigned char Alds[16 * 768];  // 12 KB
    __shared__ __align__(16) unsigned char Hlds[16 * 256];  // 4 KB
    int t = threadIdx.x;
    int b0 = blockIdx.x * 16;
    #pragma unroll
    for (int i = 0; i < 3; ++i){
        int idx = t + i * 256;
        int r = idx / 48, c = idx - r * 48;
        const char* sp = (c < 32)
            ? (const char*)catb + (size_t)(b0 + r) * 512 + c * 16
            : (const char*)srcb + (size_t)(b0 + r) * 256 + (c - 32) * 16;
        *(u32x4*)(Alds + r * 768 + ((c * 16) ^ ((r & 7) << 4))) = *(const u32x4*)sp;
    }
    __syncthreads();
    int w = t >> 6, l = t & 63, lr = l & 15, lg4 = l >> 4;
    int colbase = w * 32, axor = (lr & 7) << 4;
    f32x4 acc[2] = {};
    #pragma unroll
    for (int ks = 0; ks < 12; ++ks){
        int kb = ks * 64 + lg4 * 16;
        bf16x8 a0 = *(const bf16x8*)(Alds + lr * 768 + (kb ^ axor));
        #pragma unroll
        for (int cf = 0; cf < 2; ++cf){
            bf16x8 bq = *(const bf16x8*)((const char*)m1wb + (size_t)(colbase + cf * 16 + lr) * 768 + kb);
            acc[cf] = __builtin_amdgcn_mfma_f32_16x16x32_bf16(a0, bq, acc[cf], 0, 0, 0);
        }
    }
    #pragma unroll
    for (int cf = 0; cf < 2; ++cf){
        int col = colbase + cf * 16 + lr;
        float mb = m1b[col];
        #pragma unroll
        for (int j = 0; j < 4; ++j){
            int row = lg4 * 4 + j;
            float v = fmaxf(acc[cf][j] + mb, 0.f);
            *(bf16*)(Hlds + row * 256 + ((col * 2) ^ ((row & 7) << 4))) = f2b(v);
        }
    }
    __syncthreads();
    f32x4 acc2[2] = {};
    #pragma unroll
    for (int ks = 0; ks < 4; ++ks){
        int kb = ks * 64 + lg4 * 16;
        bf16x8 a0 = *(const bf16x8*)(Hlds + lr * 256 + (kb ^ axor));
        #pragma unroll
        for (int cf = 0; cf < 2; ++cf){
            bf16x8 bq = *(const bf16x8*)((const char*)m2wb + (size_t)(colbase + cf * 16 + lr) * 256 + kb);
            acc2[cf] = __builtin_amdgcn_mfma_f32_16x16x32_bf16(a0, bq, acc2[cf], 0, 0, 0);
        }
    }
    #pragma unroll
    for (int cf = 0; cf < 2; ++cf){
        int col = colbase + cf * 16 + lr;
        float mb = m2b[col];
        #pragma unroll
        for (int j = 0; j < 4; ++j){
            int row = lg4 * 4 + j;
            outF[(size_t)(b0 + row) * cD + col] = acc2[cf][j] + mb;
        }
    }
}

extern "C" void kernel_launch(void* const* d_in, const int* in_sizes, int n_in,
                              void* d_out, int out_size, void* d_ws, size_t ws_size,
                              hipStream_t stream) {
    const float* src    = (const float*)d_in[0];
    const float* src_t  = (const float*)d_in[1];
    const float* seq    = (const float*)d_in[2];
    const float* seq_t  = (const float*)d_in[3];
    const float* seq_e  = (const float*)d_in[4];
    const float* Wq     = (const float*)d_in[5];
    const float* Wk     = (const float*)d_in[6];
    const float* Wv     = (const float*)d_in[7];
    const float* rpri   = (const float*)d_in[8];
    const float* fc_w   = (const float*)d_in[9];
    const float* fc_b   = (const float*)d_in[10];
    const float* ln1g   = (const float*)d_in[11];
    const float* ln1b   = (const float*)d_in[12];
    const float* ln2g   = (const float*)d_in[13];
    const float* ln2b   = (const float*)d_in[14];
    const float* ln3g   = (const float*)d_in[15];
    const float* ln3b   = (const float*)d_in[16];
    const float* m1w    = (const float*)d_in[17];
    const float* m1b    = (const float*)d_in[18];
    const float* m2w    = (const float*)d_in[19];
    const float* m2b    = (const float*)d_in[20];
    const int*  etype   = (const int*)d_in[21];
    const int*  utype   = (const int*)d_in[22];
    const int*  maskp   = (const int*)d_in[24];

    // workspace layout (bf16 regions, then ints)
    bf16*  qcatb  = (bf16*)d_ws;                           // B*DM
    bf16*  kvecL  = qcatb + (size_t)cB * cDM;              // BN*D (LN half only)
    bf16*  Wqb    = kvecL + (size_t)cBN * cD;              // NE*DM*DM
    bf16*  Wvb    = Wqb + (size_t)cNE * cDM * cDM;         // NE*DM*DM
    bf16*  WkT    = Wvb + (size_t)cNE * cDM * cDM;         // NE*DM*DM
    bf16*  Qeb    = WkT + (size_t)cNE * cDM * cDM;         // B*NE*DM
    bf16*  qk     = Qeb + (size_t)cB * cNE * cDM;          // B*NE*H*DM
    bf16*  sbuf   = qk + (size_t)cB * cNE * cH * cDM;      // B*EH*DM
    bf16*  ovb    = sbuf + (size_t)cB * cEH * cDM;         // B*DM
    bf16*  catb   = ovb + (size_t)cB * cDM;                // B*DM
    bf16*  srcb   = catb + (size_t)cB * cDM;               // B*D
    bf16*  fcwb   = srcb + (size_t)cB * cD;                // NU*DM*DM
    bf16*  m1wb   = fcwb + (size_t)cNU * cDM * cDM;        // D*(DM+D)
    bf16*  m2wb   = m1wb + (size_t)cD * (cDM + cD);        // D*D
    int*   ucnt   = (int*)(m2wb + (size_t)cD * cD);        // 4
    int*   uidx   = ucnt + 4;                              // NU*B
    int*   utiles = uidx + (size_t)cNU * cB;               // MAXUT
    int*   nutiles= utiles + MAXUT;                        // 1

    float* outF = (float*)d_out;
    float* outA = outF + (size_t)cB * cD;

    k_wprep<<<dim3(384, 6), dim3(256), 0, stream>>>(Wq, Wk, Wv, fc_w, m1w, m2w,
                                                    Wqb, Wvb, WkT, fcwb, m1wb, m2wb);
    k_qprep<<<dim3(cB / 4), dim3(256), 0, stream>>>(src, src_t, ln1g, ln1b, qcatb, srcb);
    k_ln<<<dim3(cBN / 8), dim3(256), 0, stream>>>(seq, seq_e, ln2g, ln2b, kvecL);
    k_uprep<<<dim3(1), dim3(256), 0, stream>>>(utype, ucnt, uidx, utiles, nutiles);
    k_gemmQ<<<dim3(cB / 32, cNE), dim3(256), 0, stream>>>(qcatb, Wqb, Qeb);
    k_qk<<<dim3(cB / 32, cNE, cH), dim3(256), 0, stream>>>(Qeb, WkT, rpri, utype, qk);
    k_attn<<<dim3(cB), dim3(256), 0, stream>>>(kvecL, seq_t, qk, etype, maskp, outA, sbuf);
    k_sv<<<dim3(cB / 32, cH), dim3(64), 0, stream>>>(sbuf, Wvb, ovb);
    k_fcln<<<dim3(MAXUT), dim3(256), 0, stream>>>(ovb, fcwb, fc_b, ln3g, ln3b,
                                                  ucnt, uidx, utiles, nutiles, catb);
    k_mlp<<<dim3(cB / 16), dim3(256), 0, stream>>>(catb, srcb, m1wb, m1b, m2wb, m2b, outF);
}

// Round 18
// 151.943 us; speedup vs baseline: 1.2817x; 1.1363x over previous
//
#include <hip/hip_runtime.h>
#include <hip/hip_bf16.h>

typedef __hip_bfloat16 bf16;
typedef __attribute__((ext_vector_type(8))) __bf16 bf16x8;
typedef __attribute__((ext_vector_type(4))) float f32x4;
typedef __attribute__((ext_vector_type(4))) unsigned int u32x4;

static __device__ __forceinline__ float b2f(bf16 x){ return __bfloat162float(x); }
static __device__ __forceinline__ bf16  f2b(float x){ return __float2bfloat16(x); }

constexpr int cB = 2048, cN = 64, cD = 128, cDM = 256, cH = 8, cNE = 6, cNU = 4;
constexpr int cBN = cB * cN;                 // 131072 rows
constexpr float LNEPS = 1e-5f;
constexpr float RSQ32 = 0.17677669529663687f; // 1/sqrt(32)
constexpr int MAXUT = 80;                     // >= 2048/32 + 4
constexpr int cEH = cNE * cH;                 // 48

// kvT swizzle key: varies with BOTH i&7 and (i>>3)&7.
static __device__ __forceinline__ int kvkey(int row){ return ((row ^ (row >> 3)) & 7) << 4; }

// ------------- fused weight prep: Wq/Wv/fc/m1/m2 bf16 convert, Wk transpose -------------
__global__ __launch_bounds__(256) void k_wprep(const float* __restrict__ Wq,
        const float* __restrict__ Wk, const float* __restrict__ Wv,
        const float* __restrict__ fc_w, const float* __restrict__ m1w,
        const float* __restrict__ m2w,
        bf16* __restrict__ Wqb, bf16* __restrict__ Wvb, bf16* __restrict__ WkT,
        bf16* __restrict__ fcwb, bf16* __restrict__ m1wb, bf16* __restrict__ m2wb){
    __shared__ bf16 tile[32][33];
    int y = blockIdx.y, x = blockIdx.x, t = threadIdx.x;
    if (y == 5){
        int e = x >> 6, tb = x & 63;
        int tr = tb >> 3, tc = tb & 7;
        int r = t >> 3, c4 = (t & 7) * 4;
        float4 v = *(const float4*)(Wk + ((size_t)e * 256 + tr * 32 + r) * 256 + tc * 32 + c4);
        tile[r][c4 + 0] = f2b(v.x); tile[r][c4 + 1] = f2b(v.y);
        tile[r][c4 + 2] = f2b(v.z); tile[r][c4 + 3] = f2b(v.w);
        __syncthreads();
        union { bf16 h[4]; uint2 u; } p;
        p.h[0] = tile[c4 + 0][r]; p.h[1] = tile[c4 + 1][r];
        p.h[2] = tile[c4 + 2][r]; p.h[3] = tile[c4 + 3][r];
        *(uint2*)&WkT[((size_t)e * 256 + tc * 32 + r) * 256 + tr * 32 + c4] = p.u;
        return;
    }
    const float* s; bf16* d; int n4;
    switch (y){
        case 0: s = Wq;   d = Wqb;  n4 = cNE * cDM * cDM / 4; break;
        case 1: s = Wv;   d = Wvb;  n4 = cNE * cDM * cDM / 4; break;
        case 2: s = fc_w; d = fcwb; n4 = cNU * cDM * cDM / 4; break;
        case 3: s = m1w;  d = m1wb; n4 = cD * (cDM + cD) / 4; break;
        default: s = m2w; d = m2wb; n4 = cD * cD / 4; break;
    }
    int i = x * 256 + t;
    if (i >= n4) return;
    float4 v = ((const float4*)s)[i];
    union { bf16 h[4]; uint2 u; } p;
    p.h[0] = f2b(v.x); p.h[1] = f2b(v.y); p.h[2] = f2b(v.z); p.h[3] = f2b(v.w);
    *(uint2*)&d[(size_t)i * 4] = p.u;
}

// ---------------- qcatb[b] = bf16([ln1(src[b]), src_t[b]]); srcb = bf16(src) ----------------
__global__ __launch_bounds__(256) void k_qprep(const float* __restrict__ src,
        const float* __restrict__ src_t, const float* __restrict__ g1,
        const float* __restrict__ b1, bf16* __restrict__ qcatb,
        bf16* __restrict__ srcb){
    int lane = threadIdx.x & 63;
    int b = blockIdx.x * 4 + (threadIdx.x >> 6);
    const float* s = src + b * cD;
    float x0 = s[lane], x1 = s[lane + 64];
    srcb[b * cD + lane]      = f2b(x0);
    srcb[b * cD + lane + 64] = f2b(x1);
    float sm = x0 + x1;
    #pragma unroll
    for (int m = 32; m; m >>= 1) sm += __shfl_xor(sm, m);
    float mu = sm * (1.0f / cD);
    float d0 = x0 - mu, d1 = x1 - mu;
    float vs = d0 * d0 + d1 * d1;
    #pragma unroll
    for (int m = 32; m; m >>= 1) vs += __shfl_xor(vs, m);
    float rs = rsqrtf(vs * (1.0f / cD) + LNEPS);
    bf16* q = qcatb + b * cDM;
    q[lane]        = f2b(d0 * rs * g1[lane] + b1[lane]);
    q[lane + 64]   = f2b(d1 * rs * g1[lane + 64] + b1[lane + 64]);
    q[cD + lane]      = f2b(src_t[b * cD + lane]);
    q[cD + lane + 64] = f2b(src_t[b * cD + lane + 64]);
}

// ------------- utype gather: counts, index lists, tile list (single block) -------------
__global__ __launch_bounds__(256) void k_uprep(const int* __restrict__ utype,
        int* __restrict__ ucnt, int* __restrict__ uidx,
        int* __restrict__ utiles, int* __restrict__ nutiles){
    __shared__ int lc[cNU], cur[cNU];
    int t = threadIdx.x;
    if (t < cNU){ lc[t] = 0; cur[t] = 0; }
    __syncthreads();
    #pragma unroll
    for (int i = 0; i < 8; ++i) atomicAdd(&lc[utype[t + i * 256]], 1);
    __syncthreads();
    if (t < cNU) ucnt[t] = lc[t];
    #pragma unroll
    for (int i = 0; i < 8; ++i){
        int b = t + i * 256;
        int u = utype[b];
        int pos = atomicAdd(&cur[u], 1);
        uidx[u * cB + pos] = b;
    }
    __syncthreads();
    if (t == 0){
        int s = 0;
        for (int u = 0; u < cNU; ++u){
            int nt = (lc[u] + 31) >> 5;
            for (int k = 0; k < nt; ++k) utiles[s + k] = (u << 16) | k;
            s += nt;
        }
        *nutiles = s;
    }
}

// ------------- Qeb[b][e] = bf16(qcat[b] @ Wq[e].T) via MFMA -------------
__global__ __launch_bounds__(256) void k_gemmQ(const bf16* __restrict__ qcatb,
        const bf16* __restrict__ Wqb, bf16* __restrict__ Qeb){
    int t = threadIdx.x, w = t >> 6, l = t & 63;
    int lr = l & 15, lg4 = l >> 4;
    int b0 = blockIdx.x * 32, e = blockIdx.y;
    const char* A  = (const char*)qcatb + (size_t)b0 * 512;
    const char* Wq = (const char*)(Wqb + (size_t)e * 65536);
    int colbase = w * 64;
    f32x4 acc[2][4] = {};
    #pragma unroll
    for (int ks = 0; ks < 8; ++ks){
        int kb = ks * 64 + lg4 * 16;
        bf16x8 a0 = *(const bf16x8*)(A + (size_t)lr * 512 + kb);
        bf16x8 a1 = *(const bf16x8*)(A + (size_t)(16 + lr) * 512 + kb);
        #pragma unroll
        for (int cf = 0; cf < 4; ++cf){
            bf16x8 bq = *(const bf16x8*)(Wq + (size_t)(colbase + cf * 16 + lr) * 512 + kb);
            acc[0][cf] = __builtin_amdgcn_mfma_f32_16x16x32_bf16(a0, bq, acc[0][cf], 0, 0, 0);
            acc[1][cf] = __builtin_amdgcn_mfma_f32_16x16x32_bf16(a1, bq, acc[1][cf], 0, 0, 0);
        }
    }
    #pragma unroll
    for (int rf = 0; rf < 2; ++rf)
        #pragma unroll
        for (int cf = 0; cf < 4; ++cf)
            #pragma unroll
            for (int j = 0; j < 4; ++j){
                int b = b0 + rf * 16 + lg4 * 4 + j;
                Qeb[((size_t)b * cNE + e) * cDM + colbase + cf * 16 + lr] = f2b(acc[rf][cf][j]);
            }
}

// ------------- qk[b][e][h][:] = (pri/sqrt(32)) * (Qe[b,e,head h] @ Wk[e][head h, :]) -------------
__global__ __launch_bounds__(256) void k_qk(const bf16* __restrict__ Qeb,
        const bf16* __restrict__ WkT, const float* __restrict__ rpri,
        const int* __restrict__ utype, bf16* __restrict__ qk){
    __shared__ float s_pri[32];
    int t = threadIdx.x, w = t >> 6, l = t & 63;
    int lr = l & 15, lg4 = l >> 4;
    int b0 = blockIdx.x * 32, e = blockIdx.y, h = blockIdx.z;
    if (t < 32) s_pri[t] = rpri[utype[b0 + t] * cNE + e] * RSQ32;
    __syncthreads();
    int colbase = w * 64;
    bf16x8 a0 = *(const bf16x8*)(Qeb + ((size_t)(b0 + lr) * cNE + e) * cDM + h * 32 + lg4 * 8);
    bf16x8 a1 = *(const bf16x8*)(Qeb + ((size_t)(b0 + 16 + lr) * cNE + e) * cDM + h * 32 + lg4 * 8);
    f32x4 acc[2][4] = {};
    #pragma unroll
    for (int cf = 0; cf < 4; ++cf){
        bf16x8 bq = *(const bf16x8*)(WkT + ((size_t)e * 256 + colbase + cf * 16 + lr) * 256 + h * 32 + lg4 * 8);
        acc[0][cf] = __builtin_amdgcn_mfma_f32_16x16x32_bf16(a0, bq, acc[0][cf], 0, 0, 0);
        acc[1][cf] = __builtin_amdgcn_mfma_f32_16x16x32_bf16(a1, bq, acc[1][cf], 0, 0, 0);
    }
    #pragma unroll
    for (int rf = 0; rf < 2; ++rf)
        #pragma unroll
        for (int cf = 0; cf < 4; ++cf)
            #pragma unroll
            for (int j = 0; j < 4; ++j){
                int bb = b0 + rf * 16 + lg4 * 4 + j;
                float sc = s_pri[rf * 16 + lg4 * 4 + j];
                qk[(((size_t)bb * cNE + e) * cH + h) * cDM + colbase + cf * 16 + lr]
                    = f2b(acc[rf][cf][j] * sc);
            }
}

// ------------- per-b: fused ln2 + logits MFMA + softmax + s = P'@kv -------------
// ln2 computed in-register (row shared by 4 lg4-threads; shfl_xor 16/32 reduce);
// k_ln kernel and kvecL buffer eliminated. Single-read of seq/seq_e/seq_t.
__global__ __launch_bounds__(256, 4) void k_attn(const float* __restrict__ seq,
        const float* __restrict__ seq_e, const float* __restrict__ seq_t,
        const float* __restrict__ g2, const float* __restrict__ b2v,
        const bf16* __restrict__ qk, const int* __restrict__ etype,
        const int* __restrict__ maskp, float* __restrict__ outA,
        bf16* __restrict__ sbuf){
    __shared__ __align__(16) unsigned char kvT[16384];
    __shared__ __align__(16) unsigned char uB[64 * 49 * 4];
    __shared__ int s_e[cN], s_m[cN];
    int b = blockIdx.x, t = threadIdx.x;
    if (t < cN){ s_e[t] = etype[b * cN + t]; s_m[t] = maskp[b * cN + t]; }
    int w = t >> 6, l = t & 63, lr = l & 15, lg4 = l >> 4;
    int an = w * 16 + lr;                  // this thread's A-row (n index)
    const float* sq = seq   + ((size_t)b * cN + an) * cD;
    const float* se = seq_e + ((size_t)b * cN + an) * cD;
    const float* st = seq_t + ((size_t)b * cN + an) * cD;
    // ---- fused ln2: this thread holds elements ks*32 + lg4*8 + j (ks<4, j<8) ----
    float xv[4][8];
    float sm = 0.f;
    #pragma unroll
    for (int ks = 0; ks < 4; ++ks){
        int base = ks * 32 + lg4 * 8;
        float4 a0 = *(const float4*)(sq + base);
        float4 a1 = *(const float4*)(sq + base + 4);
        float4 e0 = *(const float4*)(se + base);
        float4 e1 = *(const float4*)(se + base + 4);
        xv[ks][0] = a0.x + e0.x; xv[ks][1] = a0.y + e0.y;
        xv[ks][2] = a0.z + e0.z; xv[ks][3] = a0.w + e0.w;
        xv[ks][4] = a1.x + e1.x; xv[ks][5] = a1.y + e1.y;
        xv[ks][6] = a1.z + e1.z; xv[ks][7] = a1.w + e1.w;
        #pragma unroll
        for (int j = 0; j < 8; ++j) sm += xv[ks][j];
    }
    sm += __shfl_xor(sm, 16); sm += __shfl_xor(sm, 32);
    float mu = sm * (1.0f / cD);
    float vs = 0.f;
    #pragma unroll
    for (int ks = 0; ks < 4; ++ks)
        #pragma unroll
        for (int j = 0; j < 8; ++j){ xv[ks][j] -= mu; vs += xv[ks][j] * xv[ks][j]; }
    vs += __shfl_xor(vs, 16); vs += __shfl_xor(vs, 32);
    float rs = rsqrtf(vs * (1.0f / cD) + LNEPS);
    bf16x8 afk[8];
    #pragma unroll
    for (int ks = 0; ks < 4; ++ks){
        int base = ks * 32 + lg4 * 8;
        float4 g0 = *(const float4*)(g2 + base);
        float4 g1v = *(const float4*)(g2 + base + 4);
        float4 bb0 = *(const float4*)(b2v + base);
        float4 bb1 = *(const float4*)(b2v + base + 4);
        union { bf16x8 v; bf16 hh[8]; } ua;
        ua.hh[0] = f2b(xv[ks][0] * rs * g0.x + bb0.x);
        ua.hh[1] = f2b(xv[ks][1] * rs * g0.y + bb0.y);
        ua.hh[2] = f2b(xv[ks][2] * rs * g0.z + bb0.z);
        ua.hh[3] = f2b(xv[ks][3] * rs * g0.w + bb0.w);
        ua.hh[4] = f2b(xv[ks][4] * rs * g1v.x + bb1.x);
        ua.hh[5] = f2b(xv[ks][5] * rs * g1v.y + bb1.y);
        ua.hh[6] = f2b(xv[ks][6] * rs * g1v.z + bb1.z);
        ua.hh[7] = f2b(xv[ks][7] * rs * g1v.w + bb1.w);
        afk[ks] = ua.v;
    }
    // ---- logits MFMA (A-frags in regs; seq_t half converted inline) ----
    const char* Bq = (const char*)(qk + (size_t)b * (cNE * cH * cDM));
    f32x4 acc[3] = {};
    #pragma unroll
    for (int ks = 0; ks < 4; ++ks){
        int kb = ks * 64 + lg4 * 16;
        #pragma unroll
        for (int cf = 0; cf < 3; ++cf){
            bf16x8 bq = *(const bf16x8*)(Bq + (size_t)(cf * 16 + lr) * 512 + kb);
            acc[cf] = __builtin_amdgcn_mfma_f32_16x16x32_bf16(afk[ks], bq, acc[cf], 0, 0, 0);
        }
    }
    #pragma unroll
    for (int ks = 4; ks < 8; ++ks){
        int kb = ks * 64 + lg4 * 16;
        int base = (ks - 4) * 32 + lg4 * 8;
        float4 f0 = *(const float4*)(st + base);
        float4 f1 = *(const float4*)(st + base + 4);
        union { bf16x8 v; bf16 hh[8]; } ua;
        ua.hh[0] = f2b(f0.x); ua.hh[1] = f2b(f0.y); ua.hh[2] = f2b(f0.z); ua.hh[3] = f2b(f0.w);
        ua.hh[4] = f2b(f1.x); ua.hh[5] = f2b(f1.y); ua.hh[6] = f2b(f1.z); ua.hh[7] = f2b(f1.w);
        afk[ks] = ua.v;
        #pragma unroll
        for (int cf = 0; cf < 3; ++cf){
            bf16x8 bq = *(const bf16x8*)(Bq + (size_t)(cf * 16 + lr) * 512 + kb);
            acc[cf] = __builtin_amdgcn_mfma_f32_16x16x32_bf16(afk[ks], bq, acc[cf], 0, 0, 0);
        }
    }
    float* lgAll = (float*)uB;
    #pragma unroll
    for (int cf = 0; cf < 3; ++cf)
        #pragma unroll
        for (int j = 0; j < 4; ++j)
            lgAll[(w * 16 + lg4 * 4 + j) * 49 + cf * 16 + lr] = acc[cf][j];
    __syncthreads();                       // lgAll + s_e ready
    // softmax: wave w handles heads w and w+4; lane l == n
    int n = l;
    int e = s_e[n];
    bool msk = s_m[n] != 0;
    float v0 = msk ? -1e10f : lgAll[n * 49 + e * 8 + w];
    float v1 = msk ? -1e10f : lgAll[n * 49 + e * 8 + w + 4];
    __syncthreads();                       // lgAll dead; uB becomes Pp
    float m0 = v0, m1v = v1;
    #pragma unroll
    for (int m = 32; m; m >>= 1){
        m0 = fmaxf(m0, __shfl_xor(m0, m));
        m1v = fmaxf(m1v, __shfl_xor(m1v, m));
    }
    float e0 = expf(v0 - m0), e1 = expf(v1 - m1v);
    float sm0 = e0, sm1 = e1;
    #pragma unroll
    for (int m = 32; m; m >>= 1){
        sm0 += __shfl_xor(sm0, m);
        sm1 += __shfl_xor(sm1, m);
    }
    float p0 = e0 / sm0, p1 = e1 / sm1;
    outA[((size_t)w * cB + b) * cN + n] = p0;
    outA[((size_t)(w + 4) * cB + b) * cN + n] = p1;
    // P' build: rows e*8+h, cols n, bf16 swizzled (128B rows)
    unsigned char* Pp = uB;
    bf16 bp0 = f2b(p0), bp1 = f2b(p1);
    bf16 bz = f2b(0.f);
    #pragma unroll
    for (int ee = 0; ee < cNE; ++ee){
        int r0 = ee * 8 + w, r1 = ee * 8 + w + 4;
        *(bf16*)(Pp + r0 * 128 + ((n * 2) ^ ((r0 & 7) << 4))) = (e == ee) ? bp0 : bz;
        *(bf16*)(Pp + r1 * 128 + ((n * 2) ^ ((r1 & 7) << 4))) = (e == ee) ? bp1 : bz;
    }
    // stage kvT(0) from afk[0..3] registers
    #pragma unroll
    for (int ks = 0; ks < 4; ++ks){
        union { bf16x8 v; bf16 hh[8]; } ua; ua.v = afk[ks];
        int i0 = ks * 32 + lg4 * 8;
        #pragma unroll
        for (int j = 0; j < 8; ++j){
            int row = i0 + j;
            *(bf16*)(kvT + row * 128 + ((an * 2) ^ kvkey(row))) = ua.hh[j];
        }
    }
    __syncthreads();                       // Pp + kvT(0) ready
    char* sbg = (char*)sbuf + (size_t)b * (cEH * cDM * 2);
    #pragma unroll
    for (int hf = 0; hf < 2; ++hf){
        if (hf == 1){
            // stage kvT(1) from afk[4..7] registers
            #pragma unroll
            for (int ks = 4; ks < 8; ++ks){
                union { bf16x8 v; bf16 hh[8]; } ua; ua.v = afk[ks];
                int i0 = (ks - 4) * 32 + lg4 * 8;
                #pragma unroll
                for (int j = 0; j < 8; ++j){
                    int row = i0 + j;
                    *(bf16*)(kvT + row * 128 + ((an * 2) ^ kvkey(row))) = ua.hh[j];
                }
            }
            __syncthreads();               // kvT(1) ready
        }
        // s-MFMA: wave w owns local i-cols [32w, 32w+32); full K=64
        f32x4 sacc[3][2] = {};
        #pragma unroll
        for (int ks = 0; ks < 2; ++ks){
            int kb = ks * 64 + lg4 * 16;
            bf16x8 bfr[2];
            #pragma unroll
            for (int nt = 0; nt < 2; ++nt){
                int il = w * 32 + nt * 16 + lr;
                bfr[nt] = *(const bf16x8*)(kvT + il * 128 + (kb ^ kvkey(il)));
            }
            #pragma unroll
            for (int mt = 0; mt < 3; ++mt){
                int row = mt * 16 + lr;
                bf16x8 af = *(const bf16x8*)(Pp + row * 128 + (kb ^ ((row & 7) << 4)));
                sacc[mt][0] = __builtin_amdgcn_mfma_f32_16x16x32_bf16(af, bfr[0], sacc[mt][0], 0, 0, 0);
                sacc[mt][1] = __builtin_amdgcn_mfma_f32_16x16x32_bf16(af, bfr[1], sacc[mt][1], 0, 0, 0);
            }
        }
        __syncthreads();                   // kvT reads done -> becomes bounce buffer
        #pragma unroll
        for (int mt = 0; mt < 3; ++mt)
            #pragma unroll
            for (int nt = 0; nt < 2; ++nt)
                #pragma unroll
                for (int j = 0; j < 4; ++j){
                    int eh = mt * 16 + lg4 * 4 + j;
                    int il = w * 32 + nt * 16 + lr;
                    *(bf16*)(kvT + eh * 272 + il * 2) = f2b(sacc[mt][nt][j]);
                }
        __syncthreads();                   // bounce filled
        #pragma unroll
        for (int r = 0; r < 3; ++r){
            int c3 = t + r * 256;
            int eh = c3 >> 4, off = (c3 & 15) * 16;
            *(u32x4*)(sbg + eh * 512 + hf * 256 + off) = *(const u32x4*)(kvT + eh * 272 + off);
        }
        __syncthreads();                   // bounce drained -> region reusable
    }
}

// ------------- ovb[b, c in head h] = sum_e s[b,e,h,:] . Wv[e][c,:]  (skinny GEMM) -------------
__global__ __launch_bounds__(64) void k_sv(const bf16* __restrict__ sbuf,
        const bf16* __restrict__ Wvb, bf16* __restrict__ ovb){
    int b0 = blockIdx.x * 32, h = blockIdx.y;
    int l = threadIdx.x, lr = l & 15, lg4 = l >> 4;
    const char* sb = (const char*)sbuf;
    const char* wv = (const char*)Wvb;
    f32x4 acc[2][2] = {};
    #pragma unroll
    for (int e = 0; e < cNE; ++e){
        #pragma unroll
        for (int ks = 0; ks < 8; ++ks){
            int kb = ks * 64 + lg4 * 16;
            bf16x8 a0 = *(const bf16x8*)(sb + (size_t)(b0 + lr) * (cEH * cDM * 2) + (e * 8 + h) * 512 + kb);
            bf16x8 a1 = *(const bf16x8*)(sb + (size_t)(b0 + 16 + lr) * (cEH * cDM * 2) + (e * 8 + h) * 512 + kb);
            bf16x8 b0f = *(const bf16x8*)(wv + ((size_t)e * 256 + h * 32 + lr) * 512 + kb);
            bf16x8 b1f = *(const bf16x8*)(wv + ((size_t)e * 256 + h * 32 + 16 + lr) * 512 + kb);
            acc[0][0] = __builtin_amdgcn_mfma_f32_16x16x32_bf16(a0, b0f, acc[0][0], 0, 0, 0);
            acc[0][1] = __builtin_amdgcn_mfma_f32_16x16x32_bf16(a0, b1f, acc[0][1], 0, 0, 0);
            acc[1][0] = __builtin_amdgcn_mfma_f32_16x16x32_bf16(a1, b0f, acc[1][0], 0, 0, 0);
            acc[1][1] = __builtin_amdgcn_mfma_f32_16x16x32_bf16(a1, b1f, acc[1][1], 0, 0, 0);
        }
    }
    #pragma unroll
    for (int mt = 0; mt < 2; ++mt)
        #pragma unroll
        for (int nt = 0; nt < 2; ++nt)
            #pragma unroll
            for (int j = 0; j < 4; ++j)
                ovb[(size_t)(b0 + mt * 16 + lg4 * 4 + j) * cDM + h * 32 + nt * 16 + lr]
                    = f2b(acc[mt][nt][j]);
}

// ------------- fc (grouped by utype, MFMA) + ln3 -> catb bf16 -------------
__global__ __launch_bounds__(256) void k_fcln(const bf16* __restrict__ ovb,
        const bf16* __restrict__ fcwb, const float* __restrict__ fc_b,
        const float* __restrict__ g3, const float* __restrict__ b3,
        const int* __restrict__ ucnt, const int* __restrict__ uidx,
        const int* __restrict__ utiles, const int* __restrict__ nutiles,
        bf16* __restrict__ catb){
    __shared__ __align__(16) unsigned char Alds[32 * 512];  // 16 KB
    __shared__ int s_b[32], s_v[32];
    __shared__ float redS[32][4], redQ[32][4];
    __shared__ float s_mu[32], s_rs[32];
    if ((int)blockIdx.x >= *nutiles) return;
    int t = threadIdx.x;
    int info = utiles[blockIdx.x];
    int u = info >> 16, r0 = (info & 0xffff) * 32;
    if (t < 32){
        int cu = ucnt[u];
        int nr = min(32, cu - r0);
        s_b[t] = uidx[u * cB + ((t < nr) ? r0 + t : r0)];
        s_v[t] = (t < nr);
    }
    __syncthreads();
    #pragma unroll
    for (int i = 0; i < 4; ++i){
        int idx = t + i * 256, r = idx >> 5, ck = (idx & 31) * 16;
        u32x4 dv = *(const u32x4*)((const char*)ovb + (size_t)s_b[r] * 512 + ck);
        *(u32x4*)(Alds + r * 512 + (ck ^ ((r & 7) << 4))) = dv;
    }
    __syncthreads();
    int w = t >> 6, l = t & 63, lr = l & 15, lg4 = l >> 4;
    int colbase = w * 64, axor = (lr & 7) << 4;
    const char* WB = (const char*)(fcwb + (size_t)u * 65536);
    f32x4 acc[2][4] = {};
    #pragma unroll
    for (int ks = 0; ks < 8; ++ks){
        int kb = ks * 64 + lg4 * 16;
        bf16x8 a0 = *(const bf16x8*)(Alds + lr * 512 + (kb ^ axor));
        bf16x8 a1 = *(const bf16x8*)(Alds + (16 + lr) * 512 + (kb ^ axor));
        #pragma unroll
        for (int cf = 0; cf < 4; ++cf){
            bf16x8 bq = *(const bf16x8*)(WB + (size_t)(colbase + cf * 16 + lr) * 512 + kb);
            acc[0][cf] = __builtin_amdgcn_mfma_f32_16x16x32_bf16(a0, bq, acc[0][cf], 0, 0, 0);
            acc[1][cf] = __builtin_amdgcn_mfma_f32_16x16x32_bf16(a1, bq, acc[1][cf], 0, 0, 0);
        }
    }
    float g3v[4], b3v[4];
    #pragma unroll
    for (int cf = 0; cf < 4; ++cf){
        int col = colbase + cf * 16 + lr;
        float fb = fc_b[u * cDM + col];
        g3v[cf] = g3[col]; b3v[cf] = b3[col];
        #pragma unroll
        for (int rf = 0; rf < 2; ++rf)
            #pragma unroll
            for (int j = 0; j < 4; ++j) acc[rf][cf][j] += fb;
    }
    #pragma unroll
    for (int rf = 0; rf < 2; ++rf)
        #pragma unroll
        for (int j = 0; j < 4; ++j){
            int row = rf * 16 + lg4 * 4 + j;
            float s1 = acc[rf][0][j] + acc[rf][1][j] + acc[rf][2][j] + acc[rf][3][j];
            float s2 = acc[rf][0][j] * acc[rf][0][j] + acc[rf][1][j] * acc[rf][1][j]
                     + acc[rf][2][j] * acc[rf][2][j] + acc[rf][3][j] * acc[rf][3][j];
            #pragma unroll
            for (int m = 1; m < 16; m <<= 1){ s1 += __shfl_xor(s1, m); s2 += __shfl_xor(s2, m); }
            if (lr == 0){ redS[row][w] = s1; redQ[row][w] = s2; }
        }
    __syncthreads();
    if (t < 32){
        float s1 = redS[t][0] + redS[t][1] + redS[t][2] + redS[t][3];
        float s2 = redQ[t][0] + redQ[t][1] + redQ[t][2] + redQ[t][3];
        float mu = s1 * (1.0f / cDM);
        float var = s2 * (1.0f / cDM) - mu * mu;
        s_mu[t] = mu; s_rs[t] = rsqrtf(var + LNEPS);
    }
    __syncthreads();
    #pragma unroll
    for (int rf = 0; rf < 2; ++rf)
        #pragma unroll
        for (int j = 0; j < 4; ++j){
            int row = rf * 16 + lg4 * 4 + j;
            if (!s_v[row]) continue;
            size_t bofs = (size_t)s_b[row] * cDM;
            float mu = s_mu[row], rs = s_rs[row];
            #pragma unroll
            for (int cf = 0; cf < 4; ++cf){
                int col = colbase + cf * 16 + lr;
                catb[bofs + col] = f2b((acc[rf][cf][j] - mu) * rs * g3v[cf] + b3v[cf]);
            }
        }
}

// ------------- dense MLP: hmid = relu([cat,src] @ m1w.T + m1b); out = hmid @ m2w.T + m2b -------------
__global__ __launch_bounds__(256) void k_mlp(const bf16* __restrict__ catb,
        const bf16* __restrict__ srcb, const bf16* __restrict__ m1wb,
        const float* __restrict__ m1b, const bf16* __restrict__ m2wb,
        const float* __restrict__ m2b, float* __restrict__ outF){
    __shared__ __align__(16) unsigned char Alds[16 * 768];  // 12 KB
    __shared__ __align__(16) unsigned char Hlds[16 * 256];  // 4 KB
    int t = threadIdx.x;
    int b0 = blockIdx.x * 16;
    #pragma unroll
    for (int i = 0; i < 3; ++i){
        int idx = t + i * 256;
        int r = idx / 48, c = idx - r * 48;
        const char* sp = (c < 32)
            ? (const char*)catb + (size_t)(b0 + r) * 512 + c * 16
            : (const char*)srcb + (size_t)(b0 + r) * 256 + (c - 32) * 16;
        *(u32x4*)(Alds + r * 768 + ((c * 16) ^ ((r & 7) << 4))) = *(const u32x4*)sp;
    }
    __syncthreads();
    int w = t >> 6, l = t & 63, lr = l & 15, lg4 = l >> 4;
    int colbase = w * 32, axor = (lr & 7) << 4;
    f32x4 acc[2] = {};
    #pragma unroll
    for (int ks = 0; ks < 12; ++ks){
        int kb = ks * 64 + lg4 * 16;
        bf16x8 a0 = *(const bf16x8*)(Alds + lr * 768 + (kb ^ axor));
        #pragma unroll
        for (int cf = 0; cf < 2; ++cf){
            bf16x8 bq = *(const bf16x8*)((const char*)m1wb + (size_t)(colbase + cf * 16 + lr) * 768 + kb);
            acc[cf] = __builtin_amdgcn_mfma_f32_16x16x32_bf16(a0, bq, acc[cf], 0, 0, 0);
        }
    }
    #pragma unroll
    for (int cf = 0; cf < 2; ++cf){
        int col = colbase + cf * 16 + lr;
        float mb = m1b[col];
        #pragma unroll
        for (int j = 0; j < 4; ++j){
            int row = lg4 * 4 + j;
            float v = fmaxf(acc[cf][j] + mb, 0.f);
            *(bf16*)(Hlds + row * 256 + ((col * 2) ^ ((row & 7) << 4))) = f2b(v);
        }
    }
    __syncthreads();
    f32x4 acc2[2] = {};
    #pragma unroll
    for (int ks = 0; ks < 4; ++ks){
        int kb = ks * 64 + lg4 * 16;
        bf16x8 a0 = *(const bf16x8*)(Hlds + lr * 256 + (kb ^ axor));
        #pragma unroll
        for (int cf = 0; cf < 2; ++cf){
            bf16x8 bq = *(const bf16x8*)((const char*)m2wb + (size_t)(colbase + cf * 16 + lr) * 256 + kb);
            acc2[cf] = __builtin_amdgcn_mfma_f32_16x16x32_bf16(a0, bq, acc2[cf], 0, 0, 0);
        }
    }
    #pragma unroll
    for (int cf = 0; cf < 2; ++cf){
        int col = colbase + cf * 16 + lr;
        float mb = m2b[col];
        #pragma unroll
        for (int j = 0; j < 4; ++j){
            int row = lg4 * 4 + j;
            outF[(size_t)(b0 + row) * cD + col] = acc2[cf][j] + mb;
        }
    }
}

extern "C" void kernel_launch(void* const* d_in, const int* in_sizes, int n_in,
                              void* d_out, int out_size, void* d_ws, size_t ws_size,
                              hipStream_t stream) {
    const float* src    = (const float*)d_in[0];
    const float* src_t  = (const float*)d_in[1];
    const float* seq    = (const float*)d_in[2];
    const float* seq_t  = (const float*)d_in[3];
    const float* seq_e  = (const float*)d_in[4];
    const float* Wq     = (const float*)d_in[5];
    const float* Wk     = (const float*)d_in[6];
    const float* Wv     = (const float*)d_in[7];
    const float* rpri   = (const float*)d_in[8];
    const float* fc_w   = (const float*)d_in[9];
    const float* fc_b   = (const float*)d_in[10];
    const float* ln1g   = (const float*)d_in[11];
    const float* ln1b   = (const float*)d_in[12];
    const float* ln2g   = (const float*)d_in[13];
    const float* ln2b   = (const float*)d_in[14];
    const float* ln3g   = (const float*)d_in[15];
    const float* ln3b   = (const float*)d_in[16];
    const float* m1w    = (const float*)d_in[17];
    const float* m1b    = (const float*)d_in[18];
    const float* m2w    = (const float*)d_in[19];
    const float* m2b    = (const float*)d_in[20];
    const int*  etype   = (const int*)d_in[21];
    const int*  utype   = (const int*)d_in[22];
    const int*  maskp   = (const int*)d_in[24];

    // workspace layout (bf16 regions, then ints)
    bf16*  qcatb  = (bf16*)d_ws;                           // B*DM
    bf16*  Wqb    = qcatb + (size_t)cB * cDM;              // NE*DM*DM
    bf16*  Wvb    = Wqb + (size_t)cNE * cDM * cDM;         // NE*DM*DM
    bf16*  WkT    = Wvb + (size_t)cNE * cDM * cDM;         // NE*DM*DM
    bf16*  Qeb    = WkT + (size_t)cNE * cDM * cDM;         // B*NE*DM
    bf16*  qk     = Qeb + (size_t)cB * cNE * cDM;          // B*NE*H*DM
    bf16*  sbuf   = qk + (size_t)cB * cNE * cH * cDM;      // B*EH*DM
    bf16*  ovb    = sbuf + (size_t)cB * cEH * cDM;         // B*DM
    bf16*  catb   = ovb + (size_t)cB * cDM;                // B*DM
    bf16*  srcb   = catb + (size_t)cB * cDM;               // B*D
    bf16*  fcwb   = srcb + (size_t)cB * cD;                // NU*DM*DM
    bf16*  m1wb   = fcwb + (size_t)cNU * cDM * cDM;        // D*(DM+D)
    bf16*  m2wb   = m1wb + (size_t)cD * (cDM + cD);        // D*D
    int*   ucnt   = (int*)(m2wb + (size_t)cD * cD);        // 4
    int*   uidx   = ucnt + 4;                              // NU*B
    int*   utiles = uidx + (size_t)cNU * cB;               // MAXUT
    int*   nutiles= utiles + MAXUT;                        // 1

    float* outF = (float*)d_out;
    float* outA = outF + (size_t)cB * cD;

    k_wprep<<<dim3(384, 6), dim3(256), 0, stream>>>(Wq, Wk, Wv, fc_w, m1w, m2w,
                                                    Wqb, Wvb, WkT, fcwb, m1wb, m2wb);
    k_qprep<<<dim3(cB / 4), dim3(256), 0, stream>>>(src, src_t, ln1g, ln1b, qcatb, srcb);
    k_uprep<<<dim3(1), dim3(256), 0, stream>>>(utype, ucnt, uidx, utiles, nutiles);
    k_gemmQ<<<dim3(cB / 32, cNE), dim3(256), 0, stream>>>(qcatb, Wqb, Qeb);
    k_qk<<<dim3(cB / 32, cNE, cH), dim3(256), 0, stream>>>(Qeb, WkT, rpri, utype, qk);
    k_attn<<<dim3(cB), dim3(256), 0, stream>>>(seq, seq_e, seq_t, ln2g, ln2b,
                                               qk, etype, maskp, outA, sbuf);
    k_sv<<<dim3(cB / 32, cH), dim3(64), 0, stream>>>(sbuf, Wvb, ovb);
    k_fcln<<<dim3(MAXUT), dim3(256), 0, stream>>>(ovb, fcwb, fc_b, ln3g, ln3b,
                                                  ucnt, uidx, utiles, nutiles, catb);
    k_mlp<<<dim3(cB / 16), dim3(256), 0, stream>>>(catb, srcb, m1wb, m1b, m2wb, m2b, outF);
}